// Round 14
// baseline (437.722 us; speedup 1.0000x reference)
//
#include <hip/hip_runtime.h>

// ---------------------------------------------------------------------------
// Mamba2 hybrid block. GEMMs: bf16 MFMA 16x16x32, f32 accumulate, m97-style
// global_load_lds(16B) staging with XOR bank swizzle. Small-N GEMMs use
// split-K x4 into SEPARATE partial buffers; partials summed in the
// downstream residual_rms kernel. MLP gu-GEMMs fuse SwiGLU with a 128x128
// act tile (R13: 128x64 tile gave MfmaUtil 21% — 16 MFMA/K-iter/wave didn't
// amortize staging; 128x128 doubles MFMA per staged byte). Scan: MFMA
// chunked (Mamba2 quadratic form), verified gemm_bt fragment conventions.
// ---------------------------------------------------------------------------

#define BB 4
#define LL 1024
#define DMODEL 512
#define DINNER 1024
#define NHEADS 16
#define HEADDIM 64
#define DSTATE 64
#define CONVDIM 1152        // DINNER + 2*DSTATE
#define NPROJ 2192          // D_IN_PROJ
#define NPROJ_PAD 2304      // padded to multiple of 128
#define INTER_T 2816
#define INTER_M 1536
#define NCHUNK 32
#define CHUNK 32

typedef __bf16 bf16x8 __attribute__((ext_vector_type(8)));
typedef float  f32x4  __attribute__((ext_vector_type(4)));
typedef unsigned short u16;
typedef unsigned int   u32;

__device__ __forceinline__ u16 f2bf(float x) {
    union { float f; u32 u; } v; v.f = x;
    u32 u = v.u;
    return (u16)((u + 0x7fffu + ((u >> 16) & 1u)) >> 16);
}
__device__ __forceinline__ float silu_f(float x) {
    return x / (1.f + __expf(-x));
}
__device__ __forceinline__ float bf2f(u16 w) {
    union { u32 u; float f; } a; a.u = ((u32)w) << 16; return a.f;
}

// async global->LDS, 16B per lane; LDS dest is wave-uniform base + lane*16
__device__ __forceinline__ void gld_lds16(const u16* g, u16* l) {
    __builtin_amdgcn_global_load_lds(
        (const __attribute__((address_space(1))) unsigned int*)g,
        (__attribute__((address_space(3))) unsigned int*)l, 16, 0, 0);
}

// --------------------------- block-wide sum --------------------------------
__device__ __forceinline__ float block_sum(float v) {
    #pragma unroll
    for (int off = 32; off > 0; off >>= 1) v += __shfl_xor(v, off, 64);
    __shared__ float red[4];
    int w = threadIdx.x >> 6;
    int nwv = blockDim.x >> 6;
    if ((threadIdx.x & 63) == 0) red[w] = v;
    __syncthreads();
    float tot = red[0];
    for (int i = 1; i < nwv; i++) tot += red[i];
    return tot;
}

// --------------------- f32 -> bf16 convert (all weights + hidden) ----------
#define HID_E      2097152LL   // 4096*512
#define INPROJ_P_E 1179648LL   // 2304*512
#define INPROJ_S_E 1122304LL   // 2192*512
#define OUTPROJ_E   524288LL   // 512*1024
#define GUT_E      5767168LL   // 5632*1024
#define DOWNT_E    2883584LL   // 1024*2816
#define GUM_E      1572864LL   // 3072*512
#define DOWNM_E     786432LL   // 512*1536
#define CONV_TOT_E 14811136LL

__global__ __launch_bounds__(256) void convert_all_kernel(
    const float* __restrict__ s_hid, const float* __restrict__ s_inproj,
    const float* __restrict__ s_outproj, const float* __restrict__ s_gut,
    const float* __restrict__ s_downt, const float* __restrict__ s_gum,
    const float* __restrict__ s_downm, u16* __restrict__ dst)
{
    long long idx = (long long)blockIdx.x * 256 + threadIdx.x;
    long long e = idx * 4;
    if (e >= CONV_TOT_E) return;
    const float* src; long long off, nsrc;
    long long c0 = HID_E;
    long long c1 = c0 + INPROJ_P_E;
    long long c2 = c1 + OUTPROJ_E;
    long long c3 = c2 + GUT_E;
    long long c4 = c3 + DOWNT_E;
    long long c5 = c4 + GUM_E;
    if      (e < c0) { src = s_hid;     off = e;      nsrc = HID_E; }
    else if (e < c1) { src = s_inproj;  off = e - c0; nsrc = INPROJ_S_E; }
    else if (e < c2) { src = s_outproj; off = e - c1; nsrc = OUTPROJ_E; }
    else if (e < c3) { src = s_gut;     off = e - c2; nsrc = GUT_E; }
    else if (e < c4) { src = s_downt;   off = e - c3; nsrc = DOWNT_E; }
    else if (e < c5) { src = s_gum;     off = e - c4; nsrc = GUM_E; }
    else             { src = s_downm;   off = e - c5; nsrc = DOWNM_E; }
    ushort4 r;
    if (off < nsrc) {
        float4 v = *reinterpret_cast<const float4*>(src + off);
        r.x = f2bf(v.x); r.y = f2bf(v.y); r.z = f2bf(v.z); r.w = f2bf(v.w);
    } else {
        r.x = 0; r.y = 0; r.z = 0; r.w = 0;
    }
    *reinterpret_cast<ushort4*>(dst + e) = r;
}

// ----------------------------- bf16 MFMA GEMM ------------------------------
template<bool SK>
__device__ __forceinline__ void gemm_bt_body(
    const u16* __restrict__ A, const u16* __restrict__ W,
    float* __restrict__ C, int M, int N, int K, int kLen)
{
    __shared__ u16 As[128 * 32];
    __shared__ u16 Bs[128 * 32];
    int tid = threadIdx.x;
    int m0 = blockIdx.y * 128, n0 = blockIdx.x * 128;
    int kBase = SK ? blockIdx.z * kLen : 0;
    float* Cw = SK ? C + (size_t)blockIdx.z * M * N : C;
    int wave = tid >> 6, lane = tid & 63;
    int wm = (wave >> 1) * 64, wn = (wave & 1) * 64;
    int lrow = lane & 15;
    int kq = lane >> 4;
    int kx = (lrow & 3) ^ ((lrow >> 2) & 3);
    int ko = (kq ^ kx) * 8;

    int rL = lane >> 2, cL = lane & 3;
    int cG = cL ^ ((rL & 3) ^ ((rL >> 2) & 3));
    int R0 = wave * 32 + rL;
    int R1 = R0 + 16;
    const u16* gA0 = A + (size_t)(m0 + R0) * K + kBase + cG * 8;
    const u16* gA1 = A + (size_t)(m0 + R1) * K + kBase + cG * 8;
    const u16* gB0 = W + (size_t)(n0 + R0) * K + kBase + cG * 8;
    const u16* gB1 = W + (size_t)(n0 + R1) * K + kBase + cG * 8;
    u16* lA0 = &As[(wave * 32) * 32];
    u16* lA1 = &As[(wave * 32 + 16) * 32];
    u16* lB0 = &Bs[(wave * 32) * 32];
    u16* lB1 = &Bs[(wave * 32 + 16) * 32];

    f32x4 acc[4][4];
    #pragma unroll
    for (int i = 0; i < 4; i++)
        #pragma unroll
        for (int j = 0; j < 4; j++) {
            acc[i][j][0] = 0.f; acc[i][j][1] = 0.f;
            acc[i][j][2] = 0.f; acc[i][j][3] = 0.f;
        }

    for (int kt = 0; kt < kLen; kt += 32) {
        __syncthreads();
        gld_lds16(gA0 + kt, lA0);
        gld_lds16(gA1 + kt, lA1);
        gld_lds16(gB0 + kt, lB0);
        gld_lds16(gB1 + kt, lB1);
        __syncthreads();
        bf16x8 af[4], bfr[4];
        #pragma unroll
        for (int i = 0; i < 4; i++) {
            af[i]  = *reinterpret_cast<const bf16x8*>(&As[(wm + i * 16 + lrow) * 32 + ko]);
            bfr[i] = *reinterpret_cast<const bf16x8*>(&Bs[(wn + i * 16 + lrow) * 32 + ko]);
        }
        #pragma unroll
        for (int i = 0; i < 4; i++)
            #pragma unroll
            for (int j = 0; j < 4; j++)
                acc[i][j] = __builtin_amdgcn_mfma_f32_16x16x32_bf16(af[i], bfr[j], acc[i][j], 0, 0, 0);
    }

    int rbase = m0 + wm + kq * 4;
    int cbase = n0 + wn + lrow;
    #pragma unroll
    for (int i = 0; i < 4; i++)
        #pragma unroll
        for (int j = 0; j < 4; j++)
            #pragma unroll
            for (int r = 0; r < 4; r++)
                Cw[(size_t)(rbase + i * 16 + r) * N + cbase + j * 16] = acc[i][j][r];
}

__global__ __launch_bounds__(256) void gemm_bt(
    const u16* __restrict__ A, const u16* __restrict__ W,
    float* __restrict__ C, int M, int N, int K)
{
    gemm_bt_body<false>(A, W, C, M, N, K, K);
}

__global__ __launch_bounds__(256) void gemm_bt_sk(
    const u16* __restrict__ A, const u16* __restrict__ W,
    float* __restrict__ C, int M, int N, int K, int kLen)
{
    gemm_bt_body<true>(A, W, C, M, N, K, kLen);
}

// --------------------- fused gate/up GEMM + SwiGLU (128x128) ---------------
// act[M,inter] = silu(A·Wg^T) * (A·Wu^T). Block = 128(M) x 128(N) act tile;
// B LDS holds 256 rows (gate 0..127 | up 128..255). Wave = 64x64 act tile,
// 32 MFMAs + 12 frag loads per K-iter.
__global__ __launch_bounds__(256) void gemm_swiglu(
    const u16* __restrict__ A, const u16* __restrict__ W,
    u16* __restrict__ act, int M, int inter, int K)
{
    __shared__ u16 As[128 * 32];     // 8 KB
    __shared__ u16 Bs[256 * 32];     // 16 KB
    int tid = threadIdx.x;
    int m0 = blockIdx.y * 128, n0 = blockIdx.x * 128;
    int wave = tid >> 6, lane = tid & 63;
    int wm = (wave >> 1) * 64, wn = (wave & 1) * 64;
    int lrow = lane & 15;
    int kq = lane >> 4;
    int kx = (lrow & 3) ^ ((lrow >> 2) & 3);
    int ko = (kq ^ kx) * 8;

    int rL = lane >> 2, cL = lane & 3;
    int cG = cL ^ ((rL & 3) ^ ((rL >> 2) & 3));
    // A staging: wave w -> rows w*32..+31 (2 insts)
    int R0 = wave * 32 + rL, R1 = R0 + 16;
    const u16* gA0 = A + (size_t)(m0 + R0) * K + cG * 8;
    const u16* gA1 = A + (size_t)(m0 + R1) * K + cG * 8;
    u16* lA0 = &As[(wave * 32) * 32];
    u16* lA1 = &As[(wave * 32 + 16) * 32];
    // B staging: wave w -> LDS rows w*64..+63 (4 insts); rows <128 = gate,
    // rows >=128 = up (each 16-row group is uniformly one side).
    const u16* gB[4];
    u16* lB[4];
    #pragma unroll
    for (int i = 0; i < 4; i++) {
        int rBase = wave * 64 + i * 16;
        int grow = (rBase < 128) ? (n0 + rBase + rL)
                                 : (inter + n0 + rBase - 128 + rL);
        gB[i] = W + (size_t)grow * K + cG * 8;
        lB[i] = &Bs[rBase * 32];
    }

    f32x4 accg[4][4], accu[4][4];
    #pragma unroll
    for (int i = 0; i < 4; i++)
        #pragma unroll
        for (int j = 0; j < 4; j++) {
            accg[i][j][0]=0.f; accg[i][j][1]=0.f; accg[i][j][2]=0.f; accg[i][j][3]=0.f;
            accu[i][j][0]=0.f; accu[i][j][1]=0.f; accu[i][j][2]=0.f; accu[i][j][3]=0.f;
        }

    for (int kt = 0; kt < K; kt += 32) {
        __syncthreads();
        gld_lds16(gA0 + kt, lA0);
        gld_lds16(gA1 + kt, lA1);
        #pragma unroll
        for (int i = 0; i < 4; i++)
            gld_lds16(gB[i] + kt, lB[i]);
        __syncthreads();
        bf16x8 af[4], bg[4], bu[4];
        #pragma unroll
        for (int i = 0; i < 4; i++)
            af[i] = *reinterpret_cast<const bf16x8*>(&As[(wm + i * 16 + lrow) * 32 + ko]);
        #pragma unroll
        for (int j = 0; j < 4; j++) {
            bg[j] = *reinterpret_cast<const bf16x8*>(&Bs[(wn + j * 16 + lrow) * 32 + ko]);
            bu[j] = *reinterpret_cast<const bf16x8*>(&Bs[(128 + wn + j * 16 + lrow) * 32 + ko]);
        }
        #pragma unroll
        for (int i = 0; i < 4; i++)
            #pragma unroll
            for (int j = 0; j < 4; j++) {
                accg[i][j] = __builtin_amdgcn_mfma_f32_16x16x32_bf16(af[i], bg[j], accg[i][j], 0, 0, 0);
                accu[i][j] = __builtin_amdgcn_mfma_f32_16x16x32_bf16(af[i], bu[j], accu[i][j], 0, 0, 0);
            }
    }

    // C/D layout: col = lane&15, row = (lane>>4)*4 + reg
    int rbase = m0 + wm + kq * 4;
    int cbase = n0 + wn + lrow;
    #pragma unroll
    for (int i = 0; i < 4; i++)
        #pragma unroll
        for (int j = 0; j < 4; j++)
            #pragma unroll
            for (int r = 0; r < 4; r++) {
                float g = accg[i][j][r], u = accu[i][j][r];
                act[(size_t)(rbase + i * 16 + r) * inter + cbase + j * 16] =
                    f2bf(silu_f(g) * u);
            }
}

// ----------------- conv (depthwise, causal, width 4) + dt ------------------
__global__ __launch_bounds__(256) void conv_dt_kernel(
    const float* __restrict__ zx, const float* __restrict__ conv_w,
    const float* __restrict__ conv_b, const float* __restrict__ dt_bias,
    float* __restrict__ convout, float* __restrict__ dtbuf)
{
    int idx = blockIdx.x * 256 + threadIdx.x;   // over 4096*1168
    int bl = idx / 1168;
    int c  = idx - bl * 1168;
    int l  = bl & (LL - 1);
    if (c < CONVDIM) {
        const float* col = zx + (size_t)bl * NPROJ_PAD + DINNER + c;
        float acc = conv_b[c];
        #pragma unroll
        for (int i = 0; i < 4; i++) {
            int lt = l - 3 + i;
            float v = (lt >= 0) ? col[(long long)(lt - l) * NPROJ_PAD] : 0.f;
            acc = fmaf(v, conv_w[c * 4 + i], acc);
        }
        convout[(size_t)bl * CONVDIM + c] = silu_f(acc);
    } else {
        int h = c - CONVDIM;
        float v = zx[(size_t)bl * NPROJ_PAD + 2176 + h] + dt_bias[h];
        float sp = (v > 20.f) ? v : log1pf(__expf(v));
        dtbuf[(size_t)bl * NHEADS + h] = sp;
    }
}

// -------------------- MFMA chunk scan: pass 1 ------------------------------
__global__ __launch_bounds__(64) void scan_mfma1(
    const float* __restrict__ convout, const float* __restrict__ dtbuf,
    const float* __restrict__ A_log, float* __restrict__ Sc,
    float* __restrict__ Ptot, float* __restrict__ yp0)
{
    __shared__ u16 Blds[32 * 72];    // raw B bf16 [t][n]
    __shared__ u16 Clds[32 * 72];    // raw C bf16 [t][n]
    __shared__ u16 Xt[64 * 40];      // x^T bf16 [p][t]
    __shared__ u16 Bht[64 * 40];     // (w_t*dt_t*B)^T bf16 [n][t]
    __shared__ u16 Wlds[32 * 40];    // W bf16 [t][t']
    __shared__ float dtl[32], cuml[32], warr[32];

    int blk = blockIdx.x;
    int c   = blk & 31;
    int bh  = blk >> 5;
    int b = bh >> 4, h = bh & 15;
    int lane = threadIdx.x;
    int lrow = lane & 15, kq = lane >> 4;
    size_t base = ((size_t)b * LL + (size_t)c * CHUNK) * CONVDIM;
    float Ah = -__expf(A_log[h]);

    if (lane < 32)
        dtl[lane] = dtbuf[((size_t)b * LL + (size_t)c * CHUNK + lane) * NHEADS + h];
    #pragma unroll
    for (int it = 0; it < 16; ++it) {
        int idx = it * 64 + lane;
        int t = idx >> 5, q = idx & 31;
        float4 v = *reinterpret_cast<const float4*>(
            &convout[base + (size_t)t * CONVDIM + DINNER + q * 4]);
        ushort4 r4; r4.x = f2bf(v.x); r4.y = f2bf(v.y); r4.z = f2bf(v.z); r4.w = f2bf(v.w);
        if (q < 16) *reinterpret_cast<ushort4*>(&Blds[t * 72 + q * 4]) = r4;
        else        *reinterpret_cast<ushort4*>(&Clds[t * 72 + (q - 16) * 4]) = r4;
    }
    #pragma unroll
    for (int t = 0; t < 32; ++t) {
        float v = convout[base + (size_t)t * CONVDIM + h * HEADDIM + lane];
        Xt[lane * 40 + t] = f2bf(v);
    }
    __syncthreads();

    float s_inc = 0.f, s_all = 0.f;
    #pragma unroll
    for (int j = 0; j < 32; ++j) {
        float v = dtl[j];
        s_all += v;
        if (j <= lane) s_inc += v;
    }
    if (lane < 32) {
        cuml[lane] = s_inc;
        warr[lane] = __expf(Ah * (s_all - s_inc)) * dtl[lane];
    }
    float cumTot = s_all;
    __syncthreads();

    #pragma unroll
    for (int t = 0; t < 32; ++t)
        Bht[lane * 40 + t] = f2bf(warr[t] * bf2f(Blds[t * 72 + lane]));

    f32x4 accG[2][2];
    #pragma unroll
    for (int i = 0; i < 2; i++)
        #pragma unroll
        for (int j = 0; j < 2; j++) {
            accG[i][j][0]=0.f; accG[i][j][1]=0.f; accG[i][j][2]=0.f; accG[i][j][3]=0.f;
        }
    #pragma unroll
    for (int ks = 0; ks < 2; ++ks) {
        bf16x8 af[2], bfr[2];
        #pragma unroll
        for (int i = 0; i < 2; i++) {
            af[i]  = *reinterpret_cast<const bf16x8*>(&Clds[(16*i + lrow) * 72 + ks*32 + kq*8]);
            bfr[i] = *reinterpret_cast<const bf16x8*>(&Blds[(16*i + lrow) * 72 + ks*32 + kq*8]);
        }
        #pragma unroll
        for (int i = 0; i < 2; i++)
            #pragma unroll
            for (int j = 0; j < 2; j++)
                accG[i][j] = __builtin_amdgcn_mfma_f32_16x16x32_bf16(af[i], bfr[j], accG[i][j], 0, 0, 0);
    }

    float ctp0 = cuml[lrow],      dtp0 = dtl[lrow];
    float ctp1 = cuml[16 + lrow], dtp1 = dtl[16 + lrow];
    #pragma unroll
    for (int i = 0; i < 2; i++)
        #pragma unroll
        for (int r = 0; r < 4; r++) {
            int t = 16*i + kq*4 + r;
            float ct = cuml[t];
            #pragma unroll
            for (int j = 0; j < 2; j++) {
                int tp = 16*j + lrow;
                float ctp = j ? ctp1 : ctp0;
                float dtp = j ? dtp1 : dtp0;
                float g = accG[i][j][r];
                float wv = (tp <= t) ? __expf(Ah * (ct - ctp)) * dtp * g : 0.f;
                Wlds[t * 40 + tp] = f2bf(wv);
            }
        }
    __syncthreads();

    bf16x8 xf[4];
    #pragma unroll
    for (int j = 0; j < 4; j++)
        xf[j] = *reinterpret_cast<const bf16x8*>(&Xt[(16*j + lrow) * 40 + kq*8]);
    f32x4 accY[2][4];
    #pragma unroll
    for (int i = 0; i < 2; i++) {
        bf16x8 wf = *reinterpret_cast<const bf16x8*>(&Wlds[(16*i + lrow) * 40 + kq*8]);
        #pragma unroll
        for (int j = 0; j < 4; j++) {
            accY[i][j][0]=0.f; accY[i][j][1]=0.f; accY[i][j][2]=0.f; accY[i][j][3]=0.f;
            accY[i][j] = __builtin_amdgcn_mfma_f32_16x16x32_bf16(wf, xf[j], accY[i][j], 0, 0, 0);
        }
    }

    f32x4 accS[4][4];
    #pragma unroll
    for (int j = 0; j < 4; j++) {
        bf16x8 bb = *reinterpret_cast<const bf16x8*>(&Bht[(16*j + lrow) * 40 + kq*8]);
        #pragma unroll
        for (int i = 0; i < 4; i++) {
            accS[i][j][0]=0.f; accS[i][j][1]=0.f; accS[i][j][2]=0.f; accS[i][j][3]=0.f;
            accS[i][j] = __builtin_amdgcn_mfma_f32_16x16x32_bf16(xf[i], bb, accS[i][j], 0, 0, 0);
        }
    }

    float* yb = yp0 + ((size_t)b * LL + (size_t)c * CHUNK) * DINNER + h * HEADDIM;
    #pragma unroll
    for (int i = 0; i < 2; i++)
        #pragma unroll
        for (int r = 0; r < 4; r++) {
            int t = 16*i + kq*4 + r;
            #pragma unroll
            for (int j = 0; j < 4; j++)
                yb[(size_t)t * DINNER + 16*j + lrow] = accY[i][j][r];
        }
    #pragma unroll
    for (int i = 0; i < 4; i++)
        #pragma unroll
        for (int r = 0; r < 4; r++) {
            int p = 16*i + kq*4 + r;
            #pragma unroll
            for (int j = 0; j < 4; j++)
                Sc[((size_t)(bh * 4 + j) * NCHUNK + c) * 1024 + p * 16 + lrow] = accS[i][j][r];
        }
    if (lane == 0) Ptot[bh * NCHUNK + c] = __expf(Ah * cumTot);
}

// ----------------------- chunked SSM scan: combine -------------------------
__global__ __launch_bounds__(64) void scan_combine(
    const float* __restrict__ Sc, const float* __restrict__ Ptot,
    float* __restrict__ Sinit)
{
    int blk = blockIdx.x;
    int bh = blk >> 2;
    int p = threadIdx.x;
    float carry[16];
    #pragma unroll
    for (int j = 0; j < 16; j++) carry[j] = 0.f;
    for (int c = 0; c < NCHUNK; ++c) {
        size_t row = ((size_t)blk * NCHUNK + c) * 1024 + p * 16;
        float* o = Sinit + row;
        #pragma unroll
        for (int j = 0; j < 16; j++) o[j] = carry[j];
        float P = Ptot[bh * NCHUNK + c];
        const float* si = Sc + row;
        #pragma unroll
        for (int j = 0; j < 16; j++) carry[j] = fmaf(carry[j], P, si[j]);
    }
}

// -------------------- MFMA chunk scan: pass 2 ------------------------------
__global__ __launch_bounds__(64) void scan_mfma2(
    const float* __restrict__ convout, const float* __restrict__ dtbuf,
    const float* __restrict__ A_log, const float* __restrict__ Sinit,
    float* __restrict__ yp1)
{
    __shared__ u16 Clds2[32 * 72];   // dAcum-scaled C bf16 [t][n]
    __shared__ float dtl[32], dacl[32];
    int blk = blockIdx.x;
    int c   = blk & 31;
    int bh  = blk >> 5;
    int b = bh >> 4, h = bh & 15;
    int lane = threadIdx.x;
    int lrow = lane & 15, kq = lane >> 4;
    size_t base = ((size_t)b * LL + (size_t)c * CHUNK) * CONVDIM;
    float Ah = -__expf(A_log[h]);

    if (lane < 32)
        dtl[lane] = dtbuf[((size_t)b * LL + (size_t)c * CHUNK + lane) * NHEADS + h];
    __syncthreads();
    float s_inc = 0.f;
    #pragma unroll
    for (int j = 0; j < 32; ++j) {
        float v = dtl[j];
        if (j <= lane) s_inc += v;
    }
    if (lane < 32) dacl[lane] = __expf(Ah * s_inc);
    __syncthreads();
    #pragma unroll
    for (int it = 0; it < 8; ++it) {
        int idx = it * 64 + lane;
        int t = idx >> 4, q = idx & 15;
        float sc = dacl[t];
        float4 v = *reinterpret_cast<const float4*>(
            &convout[base + (size_t)t * CONVDIM + DINNER + DSTATE + q * 4]);
        ushort4 r4;
        r4.x = f2bf(v.x * sc); r4.y = f2bf(v.y * sc);
        r4.z = f2bf(v.z * sc); r4.w = f2bf(v.w * sc);
        *reinterpret_cast<ushort4*>(&Clds2[t * 72 + q * 4]) = r4;
    }
    __syncthreads();

    f32x4 accI[2][4];
    #pragma unroll
    for (int i = 0; i < 2; i++)
        #pragma unroll
        for (int j = 0; j < 4; j++) {
            accI[i][j][0]=0.f; accI[i][j][1]=0.f; accI[i][j][2]=0.f; accI[i][j][3]=0.f;
        }
    #pragma unroll
    for (int ks = 0; ks < 2; ++ks) {
        bf16x8 ca[2];
        #pragma unroll
        for (int i = 0; i < 2; i++)
            ca[i] = *reinterpret_cast<const bf16x8*>(&Clds2[(16*i + lrow) * 72 + ks*32 + kq*8]);
        int nq = ks * 2 + (kq >> 1);
        int off = (kq & 1) * 8;
        #pragma unroll
        for (int j = 0; j < 4; j++) {
            int p = 16*j + lrow;
            const float* sp = Sinit + ((size_t)(bh * 4 + nq) * NCHUNK + c) * 1024 + p * 16 + off;
            float4 a = *reinterpret_cast<const float4*>(sp);
            float4 b4 = *reinterpret_cast<const float4*>(sp + 4);
            union { u16 us[8]; bf16x8 v; } fr;
            fr.us[0] = f2bf(a.x);  fr.us[1] = f2bf(a.y);
            fr.us[2] = f2bf(a.z);  fr.us[3] = f2bf(a.w);
            fr.us[4] = f2bf(b4.x); fr.us[5] = f2bf(b4.y);
            fr.us[6] = f2bf(b4.z); fr.us[7] = f2bf(b4.w);
            #pragma unroll
            for (int i = 0; i < 2; i++)
                accI[i][j] = __builtin_amdgcn_mfma_f32_16x16x32_bf16(ca[i], fr.v, accI[i][j], 0, 0, 0);
        }
    }

    float* yb = yp1 + ((size_t)b * LL + (size_t)c * CHUNK) * DINNER + h * HEADDIM;
    #pragma unroll
    for (int i = 0; i < 2; i++)
        #pragma unroll
        for (int r = 0; r < 4; r++) {
            int t = 16*i + kq*4 + r;
            #pragma unroll
            for (int j = 0; j < 4; j++)
                yb[(size_t)t * DINNER + 16*j + lrow] = accI[i][j][r];
        }
}

// ------------- gated RMSNorm (yp0+yp1+xD)*silu(z), bf16 out ----------------
__global__ __launch_bounds__(256) void gated_rms_kernel(
    const float* __restrict__ yp0, const float* __restrict__ yp1,
    const float* __restrict__ convout, const float* __restrict__ zx,
    const float* __restrict__ Dv, const float* __restrict__ norm_w,
    u16* __restrict__ gout)
{
    int bl = blockIdx.x;
    int c = threadIdx.x * 4;
    float4 y0 = *reinterpret_cast<const float4*>(yp0 + (size_t)bl * DINNER + c);
    float4 y1 = *reinterpret_cast<const float4*>(yp1 + (size_t)bl * DINNER + c);
    float4 xv = *reinterpret_cast<const float4*>(convout + (size_t)bl * CONVDIM + c);
    float4 zv = *reinterpret_cast<const float4*>(zx + (size_t)bl * NPROJ_PAD + c);
    float Dh = Dv[c >> 6];
    float g0 = (y0.x + y1.x + xv.x * Dh) * silu_f(zv.x);
    float g1 = (y0.y + y1.y + xv.y * Dh) * silu_f(zv.y);
    float g2 = (y0.z + y1.z + xv.z * Dh) * silu_f(zv.z);
    float g3 = (y0.w + y1.w + xv.w * Dh) * silu_f(zv.w);
    float tot = block_sum(g0 * g0 + g1 * g1 + g2 * g2 + g3 * g3);
    float sc = rsqrtf(tot * (1.f / DINNER) + 1e-5f);
    float4 nw = *reinterpret_cast<const float4*>(norm_w + c);
    ushort4 o;
    o.x = f2bf(g0 * sc * nw.x); o.y = f2bf(g1 * sc * nw.y);
    o.z = f2bf(g2 * sc * nw.z); o.w = f2bf(g3 * sc * nw.w);
    *reinterpret_cast<ushort4*>(gout + (size_t)bl * DINNER + c) = o;
}

// ---- residual + 4 split-K partials + RMSNorm (no weight), f32 out ---------
__global__ void residual_rms_sk_kernel(
    const float* __restrict__ a, const float* __restrict__ pbuf,
    float* __restrict__ outf, int ncols, int rows)
{
    int row = blockIdx.x;
    int c = threadIdx.x * 4;
    size_t slice = (size_t)rows * ncols;
    size_t off = (size_t)row * ncols + c;
    float4 va = *reinterpret_cast<const float4*>(a + off);
    float4 p0 = *reinterpret_cast<const float4*>(pbuf + off);
    float4 p1 = *reinterpret_cast<const float4*>(pbuf + slice + off);
    float4 p2 = *reinterpret_cast<const float4*>(pbuf + 2 * slice + off);
    float4 p3 = *reinterpret_cast<const float4*>(pbuf + 3 * slice + off);
    float v0 = va.x + ((p0.x + p1.x) + (p2.x + p3.x));
    float v1 = va.y + ((p0.y + p1.y) + (p2.y + p3.y));
    float v2 = va.z + ((p0.z + p1.z) + (p2.z + p3.z));
    float v3 = va.w + ((p0.w + p1.w) + (p2.w + p3.w));
    float tot = block_sum(v0 * v0 + v1 * v1 + v2 * v2 + v3 * v3);
    float sc = rsqrtf(tot / (float)ncols + 1e-5f);
    float4 o; o.x = v0 * sc; o.y = v1 * sc; o.z = v2 * sc; o.w = v3 * sc;
    *reinterpret_cast<float4*>(outf + off) = o;
}

// ------------- transpose per batch: in (R,C) -> out (C,R), dual write ------
__global__ __launch_bounds__(256) void transpose_dual_kernel(
    const float* __restrict__ in, u16* __restrict__ outb,
    float* __restrict__ outf, int R, int C)
{
    __shared__ float tile[32][33];
    int b = blockIdx.z;
    int c0 = blockIdx.x * 32, r0 = blockIdx.y * 32;
    const float* ip = in + (size_t)b * R * C;
    for (int i = threadIdx.y; i < 32; i += 8)
        tile[i][threadIdx.x] = ip[(size_t)(r0 + i) * C + c0 + threadIdx.x];
    __syncthreads();
    size_t ob = (size_t)b * R * C;
    for (int i = threadIdx.y; i < 32; i += 8) {
        float v = tile[threadIdx.x][i];
        size_t oi = ob + (size_t)(c0 + i) * R + r0 + threadIdx.x;
        outf[oi] = v;
        outb[oi] = f2bf(v);
    }
}

// ---------------------------------------------------------------------------
extern "C" void kernel_launch(void* const* d_in, const int* in_sizes, int n_in,
                              void* d_out, int out_size, void* d_ws, size_t ws_size,
                              hipStream_t stream)
{
    const float* hid      = (const float*)d_in[0];
    const float* in_proj  = (const float*)d_in[1];
    const float* conv_w   = (const float*)d_in[2];
    const float* conv_b   = (const float*)d_in[3];
    const float* dt_bias  = (const float*)d_in[4];
    const float* A_log    = (const float*)d_in[5];
    const float* Dv       = (const float*)d_in[6];
    const float* norm_w   = (const float*)d_in[7];
    const float* out_proj = (const float*)d_in[8];
    const float* gu_t     = (const float*)d_in[9];
    const float* down_t   = (const float*)d_in[10];
    const float* gu_m     = (const float*)d_in[11];
    const float* down_m   = (const float*)d_in[12];
    float* outp = (float*)d_out;

    char* ws = (char*)d_ws;
    u16* bf        = (u16*)ws;
    u16* hid_bf    = bf;
    u16* w_inproj  = bf + HID_E;
    u16* w_outproj = w_inproj + INPROJ_P_E;
    u16* w_gut     = w_outproj + OUTPROJ_E;
    u16* w_downt   = w_gut + GUT_E;
    u16* w_gum     = w_downt + DOWNT_E;
    u16* w_downm   = w_gum + GUM_E;
    size_t o = (size_t)(CONV_TOT_E * 2);
    auto alloc = [&](size_t bytes) { size_t r = o; o = (o + bytes + 255) & ~(size_t)255; return r; };
    size_t dt_off  = alloc(4096 * 16 * 4);
    size_t g_off   = alloc((size_t)4096 * 1024 * 2);
    size_t h1_off  = alloc((size_t)4096 * 512 * 4);
    size_t Pt_off  = alloc(2048 * 4);
    // ---- MLP region (live step 8+); Sc/Sinit OVERLAY it (live steps 4-5).
    size_t xtb_off = alloc((size_t)2048 * 1024 * 2);
    size_t xtf_off = alloc((size_t)2048 * 1024 * 4);
    size_t act1_off= alloc((size_t)2048 * 2816 * 2);
    size_t x2_off  = alloc((size_t)2048 * 1024 * 4);
    size_t h2b_off = alloc((size_t)4096 * 512 * 2);
    size_t h2f_off = alloc((size_t)4096 * 512 * 4);
    size_t act2_off= alloc((size_t)4096 * 1536 * 2);
    size_t pad_off = alloc((size_t)10 * 1024 * 1024);
    size_t Sc_off  = xtb_off;                          // 33.55 MB
    size_t Si_off  = xtb_off + (size_t)8192 * 1024 * 4;// 33.55 MB
    (void)pad_off;
    size_t R_off   = o;
    size_t zx_off  = R_off;
    size_t cv_off  = zx_off + (size_t)4096 * NPROJ_PAD * 4;
    size_t y_off   = cv_off + (size_t)4096 * CONVDIM * 4;
    size_t sk_off  = R_off;

    float* zx      = (float*)(ws + zx_off);
    float* convout = (float*)(ws + cv_off);
    float* ybuf    = (float*)(ws + y_off);           // yp0
    float* dtbuf   = (float*)(ws + dt_off);
    u16*   g_bf    = (u16*)(ws + g_off);
    float* h1      = (float*)(ws + h1_off);
    u16*   xt_bf   = (u16*)(ws + xtb_off);
    float* xt_f    = (float*)(ws + xtf_off);
    u16*   act1    = (u16*)(ws + act1_off);
    float* x2      = (float*)(ws + x2_off);
    u16*   h2_bf   = (u16*)(ws + h2b_off);
    float* h2_f    = (float*)(ws + h2f_off);
    u16*   act2    = (u16*)(ws + act2_off);
    float* skbuf   = (float*)(ws + sk_off);
    float* Sc      = (float*)(ws + Sc_off);          // yp1 after scan_combine
    float* Sinit   = (float*)(ws + Si_off);
    float* Ptot    = (float*)(ws + Pt_off);

    // 1) convert weights + hidden to bf16
    convert_all_kernel<<<14464, 256, 0, stream>>>(
        hid, in_proj, out_proj, gu_t, down_t, gu_m, down_m, bf);

    // 2) zxbcdt = hidden @ in_proj^T
    gemm_bt<<<dim3(NPROJ_PAD / 128, 4096 / 128), 256, 0, stream>>>(
        hid_bf, w_inproj, zx, 4096, NPROJ_PAD, 512);

    // 3) conv + dt
    conv_dt_kernel<<<18688, 256, 0, stream>>>(zx, conv_w, conv_b, dt_bias, convout, dtbuf);

    // 4) MFMA chunk scan
    scan_mfma1<<<2048, 64, 0, stream>>>(convout, dtbuf, A_log, Sc, Ptot, ybuf);
    scan_combine<<<256, 64, 0, stream>>>(Sc, Ptot, Sinit);
    scan_mfma2<<<2048, 64, 0, stream>>>(convout, dtbuf, A_log, Sinit, Sc);

    // 5) gated RMSNorm -> bf16
    gated_rms_kernel<<<4096, 256, 0, stream>>>(ybuf, Sc, convout, zx, Dv, norm_w, g_bf);

    // 6) out_proj GEMM, split-K x4 -> partials in skbuf
    gemm_bt_sk<<<dim3(512 / 128, 4096 / 128, 4), 256, 0, stream>>>(
        g_bf, w_outproj, skbuf, 4096, 512, 1024, 256);

    // 7) h1 = rms(hidden + sum partials)
    residual_rms_sk_kernel<<<4096, 128, 0, stream>>>(hid, skbuf, h1, 512, 4096);

    // 8) transpose (B,1024,512) -> (B,512,1024)
    transpose_dual_kernel<<<dim3(16, 32, 4), dim3(32, 8), 0, stream>>>(h1, xt_bf, xt_f, 1024, 512);

    // 9) token MLP fused: act1 = swiglu(xt @ gu_t^T)  (352 blocks, 128x128)
    gemm_swiglu<<<dim3(INTER_T / 128, 2048 / 128), 256, 0, stream>>>(
        xt_bf, w_gut, act1, 2048, INTER_T, 1024);

    // 10) down_t GEMM, split-K x4 -> partials in skbuf
    gemm_bt_sk<<<dim3(1024 / 128, 2048 / 128, 4), 256, 0, stream>>>(
        act1, w_downt, skbuf, 2048, 1024, 2816, 704);

    // 11) x2 = rms(xt_f + sum partials)
    residual_rms_sk_kernel<<<2048, 256, 0, stream>>>(xt_f, skbuf, x2, 1024, 2048);

    // 12) transpose back (B,512,1024) -> (B,1024,512)
    transpose_dual_kernel<<<dim3(32, 16, 4), dim3(32, 8), 0, stream>>>(x2, h2_bf, h2_f, 512, 1024);

    // 13) channel MLP fused: act2 = swiglu(h2 @ gu_m^T)  (384 blocks, 128x128)
    gemm_swiglu<<<dim3(INTER_M / 128, 4096 / 128), 256, 0, stream>>>(
        h2_bf, w_gum, act2, 4096, INTER_M, 512);

    // 14) down_m GEMM, split-K x4 -> partials in skbuf
    gemm_bt_sk<<<dim3(512 / 128, 4096 / 128, 4), 256, 0, stream>>>(
        act2, w_downm, skbuf, 4096, 512, 1536, 384);

    // 15) out = rms(h2_f + sum partials)
    residual_rms_sk_kernel<<<4096, 128, 0, stream>>>(h2_f, skbuf, outp, 512, 4096);
}

// Round 15
// 368.756 us; speedup vs baseline: 1.1870x; 1.1870x over previous
//
#include <hip/hip_runtime.h>

// ---------------------------------------------------------------------------
// Mamba2 hybrid block. GEMMs: bf16 MFMA 16x16x32, f32 accumulate, m97-style
// global_load_lds(16B) staging with XOR bank swizzle. Small-N GEMMs use
// split-K x4 into SEPARATE partial buffers; partials summed in the
// downstream residual_rms kernel. MLP gu-GEMMs fuse SwiGLU with a 128x64
// act tile (R14 lesson: 128x128 doubled acc to 32 f32x4 -> VGPR 136 ->
// occupancy cliff, MfmaUtil halved, FETCH doubled. Keep acc <= 16 f32x4).
// Scan: MFMA chunked (Mamba2 quadratic form), verified fragment conventions.
// ---------------------------------------------------------------------------

#define BB 4
#define LL 1024
#define DMODEL 512
#define DINNER 1024
#define NHEADS 16
#define HEADDIM 64
#define DSTATE 64
#define CONVDIM 1152        // DINNER + 2*DSTATE
#define NPROJ 2192          // D_IN_PROJ
#define NPROJ_PAD 2304      // padded to multiple of 128
#define INTER_T 2816
#define INTER_M 1536
#define NCHUNK 32
#define CHUNK 32

typedef __bf16 bf16x8 __attribute__((ext_vector_type(8)));
typedef float  f32x4  __attribute__((ext_vector_type(4)));
typedef unsigned short u16;
typedef unsigned int   u32;

__device__ __forceinline__ u16 f2bf(float x) {
    union { float f; u32 u; } v; v.f = x;
    u32 u = v.u;
    return (u16)((u + 0x7fffu + ((u >> 16) & 1u)) >> 16);
}
__device__ __forceinline__ float silu_f(float x) {
    return x / (1.f + __expf(-x));
}
__device__ __forceinline__ float bf2f(u16 w) {
    union { u32 u; float f; } a; a.u = ((u32)w) << 16; return a.f;
}

// async global->LDS, 16B per lane; LDS dest is wave-uniform base + lane*16
__device__ __forceinline__ void gld_lds16(const u16* g, u16* l) {
    __builtin_amdgcn_global_load_lds(
        (const __attribute__((address_space(1))) unsigned int*)g,
        (__attribute__((address_space(3))) unsigned int*)l, 16, 0, 0);
}

// --------------------------- block-wide sum --------------------------------
__device__ __forceinline__ float block_sum(float v) {
    #pragma unroll
    for (int off = 32; off > 0; off >>= 1) v += __shfl_xor(v, off, 64);
    __shared__ float red[4];
    int w = threadIdx.x >> 6;
    int nwv = blockDim.x >> 6;
    if ((threadIdx.x & 63) == 0) red[w] = v;
    __syncthreads();
    float tot = red[0];
    for (int i = 1; i < nwv; i++) tot += red[i];
    return tot;
}

// --------------------- f32 -> bf16 convert (all weights + hidden) ----------
#define HID_E      2097152LL   // 4096*512
#define INPROJ_P_E 1179648LL   // 2304*512
#define INPROJ_S_E 1122304LL   // 2192*512
#define OUTPROJ_E   524288LL   // 512*1024
#define GUT_E      5767168LL   // 5632*1024
#define DOWNT_E    2883584LL   // 1024*2816
#define GUM_E      1572864LL   // 3072*512
#define DOWNM_E     786432LL   // 512*1536
#define CONV_TOT_E 14811136LL

__global__ __launch_bounds__(256) void convert_all_kernel(
    const float* __restrict__ s_hid, const float* __restrict__ s_inproj,
    const float* __restrict__ s_outproj, const float* __restrict__ s_gut,
    const float* __restrict__ s_downt, const float* __restrict__ s_gum,
    const float* __restrict__ s_downm, u16* __restrict__ dst)
{
    long long idx = (long long)blockIdx.x * 256 + threadIdx.x;
    long long e = idx * 4;
    if (e >= CONV_TOT_E) return;
    const float* src; long long off, nsrc;
    long long c0 = HID_E;
    long long c1 = c0 + INPROJ_P_E;
    long long c2 = c1 + OUTPROJ_E;
    long long c3 = c2 + GUT_E;
    long long c4 = c3 + DOWNT_E;
    long long c5 = c4 + GUM_E;
    if      (e < c0) { src = s_hid;     off = e;      nsrc = HID_E; }
    else if (e < c1) { src = s_inproj;  off = e - c0; nsrc = INPROJ_S_E; }
    else if (e < c2) { src = s_outproj; off = e - c1; nsrc = OUTPROJ_E; }
    else if (e < c3) { src = s_gut;     off = e - c2; nsrc = GUT_E; }
    else if (e < c4) { src = s_downt;   off = e - c3; nsrc = DOWNT_E; }
    else if (e < c5) { src = s_gum;     off = e - c4; nsrc = GUM_E; }
    else             { src = s_downm;   off = e - c5; nsrc = DOWNM_E; }
    ushort4 r;
    if (off < nsrc) {
        float4 v = *reinterpret_cast<const float4*>(src + off);
        r.x = f2bf(v.x); r.y = f2bf(v.y); r.z = f2bf(v.z); r.w = f2bf(v.w);
    } else {
        r.x = 0; r.y = 0; r.z = 0; r.w = 0;
    }
    *reinterpret_cast<ushort4*>(dst + e) = r;
}

// ----------------------------- bf16 MFMA GEMM ------------------------------
template<bool SK>
__device__ __forceinline__ void gemm_bt_body(
    const u16* __restrict__ A, const u16* __restrict__ W,
    float* __restrict__ C, int M, int N, int K, int kLen)
{
    __shared__ u16 As[128 * 32];
    __shared__ u16 Bs[128 * 32];
    int tid = threadIdx.x;
    int m0 = blockIdx.y * 128, n0 = blockIdx.x * 128;
    int kBase = SK ? blockIdx.z * kLen : 0;
    float* Cw = SK ? C + (size_t)blockIdx.z * M * N : C;
    int wave = tid >> 6, lane = tid & 63;
    int wm = (wave >> 1) * 64, wn = (wave & 1) * 64;
    int lrow = lane & 15;
    int kq = lane >> 4;
    int kx = (lrow & 3) ^ ((lrow >> 2) & 3);
    int ko = (kq ^ kx) * 8;

    int rL = lane >> 2, cL = lane & 3;
    int cG = cL ^ ((rL & 3) ^ ((rL >> 2) & 3));
    int R0 = wave * 32 + rL;
    int R1 = R0 + 16;
    const u16* gA0 = A + (size_t)(m0 + R0) * K + kBase + cG * 8;
    const u16* gA1 = A + (size_t)(m0 + R1) * K + kBase + cG * 8;
    const u16* gB0 = W + (size_t)(n0 + R0) * K + kBase + cG * 8;
    const u16* gB1 = W + (size_t)(n0 + R1) * K + kBase + cG * 8;
    u16* lA0 = &As[(wave * 32) * 32];
    u16* lA1 = &As[(wave * 32 + 16) * 32];
    u16* lB0 = &Bs[(wave * 32) * 32];
    u16* lB1 = &Bs[(wave * 32 + 16) * 32];

    f32x4 acc[4][4];
    #pragma unroll
    for (int i = 0; i < 4; i++)
        #pragma unroll
        for (int j = 0; j < 4; j++) {
            acc[i][j][0] = 0.f; acc[i][j][1] = 0.f;
            acc[i][j][2] = 0.f; acc[i][j][3] = 0.f;
        }

    for (int kt = 0; kt < kLen; kt += 32) {
        __syncthreads();
        gld_lds16(gA0 + kt, lA0);
        gld_lds16(gA1 + kt, lA1);
        gld_lds16(gB0 + kt, lB0);
        gld_lds16(gB1 + kt, lB1);
        __syncthreads();
        bf16x8 af[4], bfr[4];
        #pragma unroll
        for (int i = 0; i < 4; i++) {
            af[i]  = *reinterpret_cast<const bf16x8*>(&As[(wm + i * 16 + lrow) * 32 + ko]);
            bfr[i] = *reinterpret_cast<const bf16x8*>(&Bs[(wn + i * 16 + lrow) * 32 + ko]);
        }
        #pragma unroll
        for (int i = 0; i < 4; i++)
            #pragma unroll
            for (int j = 0; j < 4; j++)
                acc[i][j] = __builtin_amdgcn_mfma_f32_16x16x32_bf16(af[i], bfr[j], acc[i][j], 0, 0, 0);
    }

    int rbase = m0 + wm + kq * 4;
    int cbase = n0 + wn + lrow;
    #pragma unroll
    for (int i = 0; i < 4; i++)
        #pragma unroll
        for (int j = 0; j < 4; j++)
            #pragma unroll
            for (int r = 0; r < 4; r++)
                Cw[(size_t)(rbase + i * 16 + r) * N + cbase + j * 16] = acc[i][j][r];
}

__global__ __launch_bounds__(256) void gemm_bt(
    const u16* __restrict__ A, const u16* __restrict__ W,
    float* __restrict__ C, int M, int N, int K)
{
    gemm_bt_body<false>(A, W, C, M, N, K, K);
}

__global__ __launch_bounds__(256) void gemm_bt_sk(
    const u16* __restrict__ A, const u16* __restrict__ W,
    float* __restrict__ C, int M, int N, int K, int kLen)
{
    gemm_bt_body<true>(A, W, C, M, N, K, kLen);
}

// --------------------- fused gate/up GEMM + SwiGLU (128x64) ----------------
// act[M,inter] = silu(A·Wg^T) * (A·Wu^T), Wg = W rows [0,inter),
// Wu = W rows [inter,2*inter). Block = 128(M) x 64(N) act tile; wave w
// computes gate+up 64x32 sub-tiles (4x2 MFMAs each). A staged once, shared.
__global__ __launch_bounds__(256) void gemm_swiglu(
    const u16* __restrict__ A, const u16* __restrict__ W,
    u16* __restrict__ act, int M, int inter, int K)
{
    __shared__ u16 As[128 * 32];
    __shared__ u16 Bgs[64 * 32];
    __shared__ u16 Bus[64 * 32];
    int tid = threadIdx.x;
    int m0 = blockIdx.y * 128, n0 = blockIdx.x * 64;
    int wave = tid >> 6, lane = tid & 63;
    int wm = (wave >> 1) * 64, wn = (wave & 1) * 32;
    int lrow = lane & 15;
    int kq = lane >> 4;
    int kx = (lrow & 3) ^ ((lrow >> 2) & 3);
    int ko = (kq ^ kx) * 8;

    int rL = lane >> 2, cL = lane & 3;
    int cG = cL ^ ((rL & 3) ^ ((rL >> 2) & 3));
    int R0 = wave * 32 + rL, R1 = R0 + 16;
    const u16* gA0 = A + (size_t)(m0 + R0) * K + cG * 8;
    const u16* gA1 = A + (size_t)(m0 + R1) * K + cG * 8;
    u16* lA0 = &As[(wave * 32) * 32];
    u16* lA1 = &As[(wave * 32 + 16) * 32];
    int wB = (wave & 1) * 32;
    int upsel = wave >> 1;
    int RB0 = wB + rL, RB1 = RB0 + 16;
    const u16* gB0 = W + (size_t)(upsel * inter + n0 + RB0) * K + cG * 8;
    const u16* gB1 = W + (size_t)(upsel * inter + n0 + RB1) * K + cG * 8;
    u16* lBb = upsel ? Bus : Bgs;
    u16* lB0 = &lBb[wB * 32];
    u16* lB1 = &lBb[(wB + 16) * 32];

    f32x4 accg[4][2], accu[4][2];
    #pragma unroll
    for (int i = 0; i < 4; i++)
        #pragma unroll
        for (int j = 0; j < 2; j++) {
            accg[i][j][0]=0.f; accg[i][j][1]=0.f; accg[i][j][2]=0.f; accg[i][j][3]=0.f;
            accu[i][j][0]=0.f; accu[i][j][1]=0.f; accu[i][j][2]=0.f; accu[i][j][3]=0.f;
        }

    for (int kt = 0; kt < K; kt += 32) {
        __syncthreads();
        gld_lds16(gA0 + kt, lA0);
        gld_lds16(gA1 + kt, lA1);
        gld_lds16(gB0 + kt, lB0);
        gld_lds16(gB1 + kt, lB1);
        __syncthreads();
        bf16x8 af[4], bg[2], bu[2];
        #pragma unroll
        for (int i = 0; i < 4; i++)
            af[i] = *reinterpret_cast<const bf16x8*>(&As[(wm + i * 16 + lrow) * 32 + ko]);
        #pragma unroll
        for (int j = 0; j < 2; j++) {
            bg[j] = *reinterpret_cast<const bf16x8*>(&Bgs[(wn + j * 16 + lrow) * 32 + ko]);
            bu[j] = *reinterpret_cast<const bf16x8*>(&Bus[(wn + j * 16 + lrow) * 32 + ko]);
        }
        #pragma unroll
        for (int i = 0; i < 4; i++)
            #pragma unroll
            for (int j = 0; j < 2; j++) {
                accg[i][j] = __builtin_amdgcn_mfma_f32_16x16x32_bf16(af[i], bg[j], accg[i][j], 0, 0, 0);
                accu[i][j] = __builtin_amdgcn_mfma_f32_16x16x32_bf16(af[i], bu[j], accu[i][j], 0, 0, 0);
            }
    }

    int rbase = m0 + wm + kq * 4;
    int cbase = n0 + wn + lrow;
    #pragma unroll
    for (int i = 0; i < 4; i++)
        #pragma unroll
        for (int j = 0; j < 2; j++)
            #pragma unroll
            for (int r = 0; r < 4; r++) {
                float g = accg[i][j][r], u = accu[i][j][r];
                act[(size_t)(rbase + i * 16 + r) * inter + cbase + j * 16] =
                    f2bf(silu_f(g) * u);
            }
}

// ----------------- conv (depthwise, causal, width 4) + dt ------------------
__global__ __launch_bounds__(256) void conv_dt_kernel(
    const float* __restrict__ zx, const float* __restrict__ conv_w,
    const float* __restrict__ conv_b, const float* __restrict__ dt_bias,
    float* __restrict__ convout, float* __restrict__ dtbuf)
{
    int idx = blockIdx.x * 256 + threadIdx.x;   // over 4096*1168
    int bl = idx / 1168;
    int c  = idx - bl * 1168;
    int l  = bl & (LL - 1);
    if (c < CONVDIM) {
        const float* col = zx + (size_t)bl * NPROJ_PAD + DINNER + c;
        float acc = conv_b[c];
        #pragma unroll
        for (int i = 0; i < 4; i++) {
            int lt = l - 3 + i;
            float v = (lt >= 0) ? col[(long long)(lt - l) * NPROJ_PAD] : 0.f;
            acc = fmaf(v, conv_w[c * 4 + i], acc);
        }
        convout[(size_t)bl * CONVDIM + c] = silu_f(acc);
    } else {
        int h = c - CONVDIM;
        float v = zx[(size_t)bl * NPROJ_PAD + 2176 + h] + dt_bias[h];
        float sp = (v > 20.f) ? v : log1pf(__expf(v));
        dtbuf[(size_t)bl * NHEADS + h] = sp;
    }
}

// -------------------- MFMA chunk scan: pass 1 ------------------------------
__global__ __launch_bounds__(64) void scan_mfma1(
    const float* __restrict__ convout, const float* __restrict__ dtbuf,
    const float* __restrict__ A_log, float* __restrict__ Sc,
    float* __restrict__ Ptot, float* __restrict__ yp0)
{
    __shared__ u16 Blds[32 * 72];    // raw B bf16 [t][n]
    __shared__ u16 Clds[32 * 72];    // raw C bf16 [t][n]
    __shared__ u16 Xt[64 * 40];      // x^T bf16 [p][t]
    __shared__ u16 Bht[64 * 40];     // (w_t*dt_t*B)^T bf16 [n][t]
    __shared__ u16 Wlds[32 * 40];    // W bf16 [t][t']
    __shared__ float dtl[32], cuml[32], warr[32];

    int blk = blockIdx.x;
    int c   = blk & 31;
    int bh  = blk >> 5;
    int b = bh >> 4, h = bh & 15;
    int lane = threadIdx.x;
    int lrow = lane & 15, kq = lane >> 4;
    size_t base = ((size_t)b * LL + (size_t)c * CHUNK) * CONVDIM;
    float Ah = -__expf(A_log[h]);

    if (lane < 32)
        dtl[lane] = dtbuf[((size_t)b * LL + (size_t)c * CHUNK + lane) * NHEADS + h];
    #pragma unroll
    for (int it = 0; it < 16; ++it) {
        int idx = it * 64 + lane;
        int t = idx >> 5, q = idx & 31;
        float4 v = *reinterpret_cast<const float4*>(
            &convout[base + (size_t)t * CONVDIM + DINNER + q * 4]);
        ushort4 r4; r4.x = f2bf(v.x); r4.y = f2bf(v.y); r4.z = f2bf(v.z); r4.w = f2bf(v.w);
        if (q < 16) *reinterpret_cast<ushort4*>(&Blds[t * 72 + q * 4]) = r4;
        else        *reinterpret_cast<ushort4*>(&Clds[t * 72 + (q - 16) * 4]) = r4;
    }
    #pragma unroll
    for (int t = 0; t < 32; ++t) {
        float v = convout[base + (size_t)t * CONVDIM + h * HEADDIM + lane];
        Xt[lane * 40 + t] = f2bf(v);
    }
    __syncthreads();

    float s_inc = 0.f, s_all = 0.f;
    #pragma unroll
    for (int j = 0; j < 32; ++j) {
        float v = dtl[j];
        s_all += v;
        if (j <= lane) s_inc += v;
    }
    if (lane < 32) {
        cuml[lane] = s_inc;
        warr[lane] = __expf(Ah * (s_all - s_inc)) * dtl[lane];
    }
    float cumTot = s_all;
    __syncthreads();

    #pragma unroll
    for (int t = 0; t < 32; ++t)
        Bht[lane * 40 + t] = f2bf(warr[t] * bf2f(Blds[t * 72 + lane]));

    f32x4 accG[2][2];
    #pragma unroll
    for (int i = 0; i < 2; i++)
        #pragma unroll
        for (int j = 0; j < 2; j++) {
            accG[i][j][0]=0.f; accG[i][j][1]=0.f; accG[i][j][2]=0.f; accG[i][j][3]=0.f;
        }
    #pragma unroll
    for (int ks = 0; ks < 2; ++ks) {
        bf16x8 af[2], bfr[2];
        #pragma unroll
        for (int i = 0; i < 2; i++) {
            af[i]  = *reinterpret_cast<const bf16x8*>(&Clds[(16*i + lrow) * 72 + ks*32 + kq*8]);
            bfr[i] = *reinterpret_cast<const bf16x8*>(&Blds[(16*i + lrow) * 72 + ks*32 + kq*8]);
        }
        #pragma unroll
        for (int i = 0; i < 2; i++)
            #pragma unroll
            for (int j = 0; j < 2; j++)
                accG[i][j] = __builtin_amdgcn_mfma_f32_16x16x32_bf16(af[i], bfr[j], accG[i][j], 0, 0, 0);
    }

    float ctp0 = cuml[lrow],      dtp0 = dtl[lrow];
    float ctp1 = cuml[16 + lrow], dtp1 = dtl[16 + lrow];
    #pragma unroll
    for (int i = 0; i < 2; i++)
        #pragma unroll
        for (int r = 0; r < 4; r++) {
            int t = 16*i + kq*4 + r;
            float ct = cuml[t];
            #pragma unroll
            for (int j = 0; j < 2; j++) {
                int tp = 16*j + lrow;
                float ctp = j ? ctp1 : ctp0;
                float dtp = j ? dtp1 : dtp0;
                float g = accG[i][j][r];
                float wv = (tp <= t) ? __expf(Ah * (ct - ctp)) * dtp * g : 0.f;
                Wlds[t * 40 + tp] = f2bf(wv);
            }
        }
    __syncthreads();

    bf16x8 xf[4];
    #pragma unroll
    for (int j = 0; j < 4; j++)
        xf[j] = *reinterpret_cast<const bf16x8*>(&Xt[(16*j + lrow) * 40 + kq*8]);
    f32x4 accY[2][4];
    #pragma unroll
    for (int i = 0; i < 2; i++) {
        bf16x8 wf = *reinterpret_cast<const bf16x8*>(&Wlds[(16*i + lrow) * 40 + kq*8]);
        #pragma unroll
        for (int j = 0; j < 4; j++) {
            accY[i][j][0]=0.f; accY[i][j][1]=0.f; accY[i][j][2]=0.f; accY[i][j][3]=0.f;
            accY[i][j] = __builtin_amdgcn_mfma_f32_16x16x32_bf16(wf, xf[j], accY[i][j], 0, 0, 0);
        }
    }

    f32x4 accS[4][4];
    #pragma unroll
    for (int j = 0; j < 4; j++) {
        bf16x8 bb = *reinterpret_cast<const bf16x8*>(&Bht[(16*j + lrow) * 40 + kq*8]);
        #pragma unroll
        for (int i = 0; i < 4; i++) {
            accS[i][j][0]=0.f; accS[i][j][1]=0.f; accS[i][j][2]=0.f; accS[i][j][3]=0.f;
            accS[i][j] = __builtin_amdgcn_mfma_f32_16x16x32_bf16(xf[i], bb, accS[i][j], 0, 0, 0);
        }
    }

    float* yb = yp0 + ((size_t)b * LL + (size_t)c * CHUNK) * DINNER + h * HEADDIM;
    #pragma unroll
    for (int i = 0; i < 2; i++)
        #pragma unroll
        for (int r = 0; r < 4; r++) {
            int t = 16*i + kq*4 + r;
            #pragma unroll
            for (int j = 0; j < 4; j++)
                yb[(size_t)t * DINNER + 16*j + lrow] = accY[i][j][r];
        }
    #pragma unroll
    for (int i = 0; i < 4; i++)
        #pragma unroll
        for (int r = 0; r < 4; r++) {
            int p = 16*i + kq*4 + r;
            #pragma unroll
            for (int j = 0; j < 4; j++)
                Sc[((size_t)(bh * 4 + j) * NCHUNK + c) * 1024 + p * 16 + lrow] = accS[i][j][r];
        }
    if (lane == 0) Ptot[bh * NCHUNK + c] = __expf(Ah * cumTot);
}

// ----------------------- chunked SSM scan: combine -------------------------
__global__ __launch_bounds__(64) void scan_combine(
    const float* __restrict__ Sc, const float* __restrict__ Ptot,
    float* __restrict__ Sinit)
{
    int blk = blockIdx.x;
    int bh = blk >> 2;
    int p = threadIdx.x;
    float carry[16];
    #pragma unroll
    for (int j = 0; j < 16; j++) carry[j] = 0.f;
    for (int c = 0; c < NCHUNK; ++c) {
        size_t row = ((size_t)blk * NCHUNK + c) * 1024 + p * 16;
        float* o = Sinit + row;
        #pragma unroll
        for (int j = 0; j < 16; j++) o[j] = carry[j];
        float P = Ptot[bh * NCHUNK + c];
        const float* si = Sc + row;
        #pragma unroll
        for (int j = 0; j < 16; j++) carry[j] = fmaf(carry[j], P, si[j]);
    }
}

// -------------------- MFMA chunk scan: pass 2 ------------------------------
__global__ __launch_bounds__(64) void scan_mfma2(
    const float* __restrict__ convout, const float* __restrict__ dtbuf,
    const float* __restrict__ A_log, const float* __restrict__ Sinit,
    float* __restrict__ yp1)
{
    __shared__ u16 Clds2[32 * 72];   // dAcum-scaled C bf16 [t][n]
    __shared__ float dtl[32], dacl[32];
    int blk = blockIdx.x;
    int c   = blk & 31;
    int bh  = blk >> 5;
    int b = bh >> 4, h = bh & 15;
    int lane = threadIdx.x;
    int lrow = lane & 15, kq = lane >> 4;
    size_t base = ((size_t)b * LL + (size_t)c * CHUNK) * CONVDIM;
    float Ah = -__expf(A_log[h]);

    if (lane < 32)
        dtl[lane] = dtbuf[((size_t)b * LL + (size_t)c * CHUNK + lane) * NHEADS + h];
    __syncthreads();
    float s_inc = 0.f;
    #pragma unroll
    for (int j = 0; j < 32; ++j) {
        float v = dtl[j];
        if (j <= lane) s_inc += v;
    }
    if (lane < 32) dacl[lane] = __expf(Ah * s_inc);
    __syncthreads();
    #pragma unroll
    for (int it = 0; it < 8; ++it) {
        int idx = it * 64 + lane;
        int t = idx >> 4, q = idx & 15;
        float sc = dacl[t];
        float4 v = *reinterpret_cast<const float4*>(
            &convout[base + (size_t)t * CONVDIM + DINNER + DSTATE + q * 4]);
        ushort4 r4;
        r4.x = f2bf(v.x * sc); r4.y = f2bf(v.y * sc);
        r4.z = f2bf(v.z * sc); r4.w = f2bf(v.w * sc);
        *reinterpret_cast<ushort4*>(&Clds2[t * 72 + q * 4]) = r4;
    }
    __syncthreads();

    f32x4 accI[2][4];
    #pragma unroll
    for (int i = 0; i < 2; i++)
        #pragma unroll
        for (int j = 0; j < 4; j++) {
            accI[i][j][0]=0.f; accI[i][j][1]=0.f; accI[i][j][2]=0.f; accI[i][j][3]=0.f;
        }
    #pragma unroll
    for (int ks = 0; ks < 2; ++ks) {
        bf16x8 ca[2];
        #pragma unroll
        for (int i = 0; i < 2; i++)
            ca[i] = *reinterpret_cast<const bf16x8*>(&Clds2[(16*i + lrow) * 72 + ks*32 + kq*8]);
        int nq = ks * 2 + (kq >> 1);
        int off = (kq & 1) * 8;
        #pragma unroll
        for (int j = 0; j < 4; j++) {
            int p = 16*j + lrow;
            const float* sp = Sinit + ((size_t)(bh * 4 + nq) * NCHUNK + c) * 1024 + p * 16 + off;
            float4 a = *reinterpret_cast<const float4*>(sp);
            float4 b4 = *reinterpret_cast<const float4*>(sp + 4);
            union { u16 us[8]; bf16x8 v; } fr;
            fr.us[0] = f2bf(a.x);  fr.us[1] = f2bf(a.y);
            fr.us[2] = f2bf(a.z);  fr.us[3] = f2bf(a.w);
            fr.us[4] = f2bf(b4.x); fr.us[5] = f2bf(b4.y);
            fr.us[6] = f2bf(b4.z); fr.us[7] = f2bf(b4.w);
            #pragma unroll
            for (int i = 0; i < 2; i++)
                accI[i][j] = __builtin_amdgcn_mfma_f32_16x16x32_bf16(ca[i], fr.v, accI[i][j], 0, 0, 0);
        }
    }

    float* yb = yp1 + ((size_t)b * LL + (size_t)c * CHUNK) * DINNER + h * HEADDIM;
    #pragma unroll
    for (int i = 0; i < 2; i++)
        #pragma unroll
        for (int r = 0; r < 4; r++) {
            int t = 16*i + kq*4 + r;
            #pragma unroll
            for (int j = 0; j < 4; j++)
                yb[(size_t)t * DINNER + 16*j + lrow] = accI[i][j][r];
        }
}

// ------------- gated RMSNorm (yp0+yp1+xD)*silu(z), bf16 out ----------------
__global__ __launch_bounds__(256) void gated_rms_kernel(
    const float* __restrict__ yp0, const float* __restrict__ yp1,
    const float* __restrict__ convout, const float* __restrict__ zx,
    const float* __restrict__ Dv, const float* __restrict__ norm_w,
    u16* __restrict__ gout)
{
    int bl = blockIdx.x;
    int c = threadIdx.x * 4;
    float4 y0 = *reinterpret_cast<const float4*>(yp0 + (size_t)bl * DINNER + c);
    float4 y1 = *reinterpret_cast<const float4*>(yp1 + (size_t)bl * DINNER + c);
    float4 xv = *reinterpret_cast<const float4*>(convout + (size_t)bl * CONVDIM + c);
    float4 zv = *reinterpret_cast<const float4*>(zx + (size_t)bl * NPROJ_PAD + c);
    float Dh = Dv[c >> 6];
    float g0 = (y0.x + y1.x + xv.x * Dh) * silu_f(zv.x);
    float g1 = (y0.y + y1.y + xv.y * Dh) * silu_f(zv.y);
    float g2 = (y0.z + y1.z + xv.z * Dh) * silu_f(zv.z);
    float g3 = (y0.w + y1.w + xv.w * Dh) * silu_f(zv.w);
    float tot = block_sum(g0 * g0 + g1 * g1 + g2 * g2 + g3 * g3);
    float sc = rsqrtf(tot * (1.f / DINNER) + 1e-5f);
    float4 nw = *reinterpret_cast<const float4*>(norm_w + c);
    ushort4 o;
    o.x = f2bf(g0 * sc * nw.x); o.y = f2bf(g1 * sc * nw.y);
    o.z = f2bf(g2 * sc * nw.z); o.w = f2bf(g3 * sc * nw.w);
    *reinterpret_cast<ushort4*>(gout + (size_t)bl * DINNER + c) = o;
}

// ---- residual + 4 split-K partials + RMSNorm (no weight), f32 out ---------
__global__ void residual_rms_sk_kernel(
    const float* __restrict__ a, const float* __restrict__ pbuf,
    float* __restrict__ outf, int ncols, int rows)
{
    int row = blockIdx.x;
    int c = threadIdx.x * 4;
    size_t slice = (size_t)rows * ncols;
    size_t off = (size_t)row * ncols + c;
    float4 va = *reinterpret_cast<const float4*>(a + off);
    float4 p0 = *reinterpret_cast<const float4*>(pbuf + off);
    float4 p1 = *reinterpret_cast<const float4*>(pbuf + slice + off);
    float4 p2 = *reinterpret_cast<const float4*>(pbuf + 2 * slice + off);
    float4 p3 = *reinterpret_cast<const float4*>(pbuf + 3 * slice + off);
    float v0 = va.x + ((p0.x + p1.x) + (p2.x + p3.x));
    float v1 = va.y + ((p0.y + p1.y) + (p2.y + p3.y));
    float v2 = va.z + ((p0.z + p1.z) + (p2.z + p3.z));
    float v3 = va.w + ((p0.w + p1.w) + (p2.w + p3.w));
    float tot = block_sum(v0 * v0 + v1 * v1 + v2 * v2 + v3 * v3);
    float sc = rsqrtf(tot / (float)ncols + 1e-5f);
    float4 o; o.x = v0 * sc; o.y = v1 * sc; o.z = v2 * sc; o.w = v3 * sc;
    *reinterpret_cast<float4*>(outf + off) = o;
}

// ------------- transpose per batch: in (R,C) -> out (C,R), dual write ------
__global__ __launch_bounds__(256) void transpose_dual_kernel(
    const float* __restrict__ in, u16* __restrict__ outb,
    float* __restrict__ outf, int R, int C)
{
    __shared__ float tile[32][33];
    int b = blockIdx.z;
    int c0 = blockIdx.x * 32, r0 = blockIdx.y * 32;
    const float* ip = in + (size_t)b * R * C;
    for (int i = threadIdx.y; i < 32; i += 8)
        tile[i][threadIdx.x] = ip[(size_t)(r0 + i) * C + c0 + threadIdx.x];
    __syncthreads();
    size_t ob = (size_t)b * R * C;
    for (int i = threadIdx.y; i < 32; i += 8) {
        float v = tile[threadIdx.x][i];
        size_t oi = ob + (size_t)(c0 + i) * R + r0 + threadIdx.x;
        outf[oi] = v;
        outb[oi] = f2bf(v);
    }
}

// ---------------------------------------------------------------------------
extern "C" void kernel_launch(void* const* d_in, const int* in_sizes, int n_in,
                              void* d_out, int out_size, void* d_ws, size_t ws_size,
                              hipStream_t stream)
{
    const float* hid      = (const float*)d_in[0];
    const float* in_proj  = (const float*)d_in[1];
    const float* conv_w   = (const float*)d_in[2];
    const float* conv_b   = (const float*)d_in[3];
    const float* dt_bias  = (const float*)d_in[4];
    const float* A_log    = (const float*)d_in[5];
    const float* Dv       = (const float*)d_in[6];
    const float* norm_w   = (const float*)d_in[7];
    const float* out_proj = (const float*)d_in[8];
    const float* gu_t     = (const float*)d_in[9];
    const float* down_t   = (const float*)d_in[10];
    const float* gu_m     = (const float*)d_in[11];
    const float* down_m   = (const float*)d_in[12];
    float* outp = (float*)d_out;

    char* ws = (char*)d_ws;
    u16* bf        = (u16*)ws;
    u16* hid_bf    = bf;
    u16* w_inproj  = bf + HID_E;
    u16* w_outproj = w_inproj + INPROJ_P_E;
    u16* w_gut     = w_outproj + OUTPROJ_E;
    u16* w_downt   = w_gut + GUT_E;
    u16* w_gum     = w_downt + DOWNT_E;
    u16* w_downm   = w_gum + GUM_E;
    size_t o = (size_t)(CONV_TOT_E * 2);
    auto alloc = [&](size_t bytes) { size_t r = o; o = (o + bytes + 255) & ~(size_t)255; return r; };
    size_t dt_off  = alloc(4096 * 16 * 4);
    size_t g_off   = alloc((size_t)4096 * 1024 * 2);
    size_t h1_off  = alloc((size_t)4096 * 512 * 4);
    size_t Pt_off  = alloc(2048 * 4);
    // ---- MLP region (live step 8+); Sc/Sinit OVERLAY it (live steps 4-5).
    size_t xtb_off = alloc((size_t)2048 * 1024 * 2);
    size_t xtf_off = alloc((size_t)2048 * 1024 * 4);
    size_t act1_off= alloc((size_t)2048 * 2816 * 2);
    size_t x2_off  = alloc((size_t)2048 * 1024 * 4);
    size_t h2b_off = alloc((size_t)4096 * 512 * 2);
    size_t h2f_off = alloc((size_t)4096 * 512 * 4);
    size_t act2_off= alloc((size_t)4096 * 1536 * 2);
    size_t pad_off = alloc((size_t)10 * 1024 * 1024);
    size_t Sc_off  = xtb_off;                          // 33.55 MB
    size_t Si_off  = xtb_off + (size_t)8192 * 1024 * 4;// 33.55 MB
    (void)pad_off;
    size_t R_off   = o;
    size_t zx_off  = R_off;
    size_t cv_off  = zx_off + (size_t)4096 * NPROJ_PAD * 4;
    size_t y_off   = cv_off + (size_t)4096 * CONVDIM * 4;
    size_t sk_off  = R_off;

    float* zx      = (float*)(ws + zx_off);
    float* convout = (float*)(ws + cv_off);
    float* ybuf    = (float*)(ws + y_off);           // yp0
    float* dtbuf   = (float*)(ws + dt_off);
    u16*   g_bf    = (u16*)(ws + g_off);
    float* h1      = (float*)(ws + h1_off);
    u16*   xt_bf   = (u16*)(ws + xtb_off);
    float* xt_f    = (float*)(ws + xtf_off);
    u16*   act1    = (u16*)(ws + act1_off);
    float* x2      = (float*)(ws + x2_off);
    u16*   h2_bf   = (u16*)(ws + h2b_off);
    float* h2_f    = (float*)(ws + h2f_off);
    u16*   act2    = (u16*)(ws + act2_off);
    float* skbuf   = (float*)(ws + sk_off);
    float* Sc      = (float*)(ws + Sc_off);          // yp1 after scan_combine
    float* Sinit   = (float*)(ws + Si_off);
    float* Ptot    = (float*)(ws + Pt_off);

    // 1) convert weights + hidden to bf16
    convert_all_kernel<<<14464, 256, 0, stream>>>(
        hid, in_proj, out_proj, gu_t, down_t, gu_m, down_m, bf);

    // 2) zxbcdt = hidden @ in_proj^T
    gemm_bt<<<dim3(NPROJ_PAD / 128, 4096 / 128), 256, 0, stream>>>(
        hid_bf, w_inproj, zx, 4096, NPROJ_PAD, 512);

    // 3) conv + dt
    conv_dt_kernel<<<18688, 256, 0, stream>>>(zx, conv_w, conv_b, dt_bias, convout, dtbuf);

    // 4) MFMA chunk scan
    scan_mfma1<<<2048, 64, 0, stream>>>(convout, dtbuf, A_log, Sc, Ptot, ybuf);
    scan_combine<<<256, 64, 0, stream>>>(Sc, Ptot, Sinit);
    scan_mfma2<<<2048, 64, 0, stream>>>(convout, dtbuf, A_log, Sinit, Sc);

    // 5) gated RMSNorm -> bf16
    gated_rms_kernel<<<4096, 256, 0, stream>>>(ybuf, Sc, convout, zx, Dv, norm_w, g_bf);

    // 6) out_proj GEMM, split-K x4 -> partials in skbuf
    gemm_bt_sk<<<dim3(512 / 128, 4096 / 128, 4), 256, 0, stream>>>(
        g_bf, w_outproj, skbuf, 4096, 512, 1024, 256);

    // 7) h1 = rms(hidden + sum partials)
    residual_rms_sk_kernel<<<4096, 128, 0, stream>>>(hid, skbuf, h1, 512, 4096);

    // 8) transpose (B,1024,512) -> (B,512,1024)
    transpose_dual_kernel<<<dim3(16, 32, 4), dim3(32, 8), 0, stream>>>(h1, xt_bf, xt_f, 1024, 512);

    // 9) token MLP fused: act1 = swiglu(xt @ gu_t^T)  (704 blocks, 128x64)
    gemm_swiglu<<<dim3(INTER_T / 64, 2048 / 128), 256, 0, stream>>>(
        xt_bf, w_gut, act1, 2048, INTER_T, 1024);

    // 10) down_t GEMM, split-K x4 -> partials in skbuf
    gemm_bt_sk<<<dim3(1024 / 128, 2048 / 128, 4), 256, 0, stream>>>(
        act1, w_downt, skbuf, 2048, 1024, 2816, 704);

    // 11) x2 = rms(xt_f + sum partials)
    residual_rms_sk_kernel<<<2048, 256, 0, stream>>>(xt_f, skbuf, x2, 1024, 2048);

    // 12) transpose back (B,512,1024) -> (B,1024,512)
    transpose_dual_kernel<<<dim3(32, 16, 4), dim3(32, 8), 0, stream>>>(x2, h2_bf, h2_f, 512, 1024);

    // 13) channel MLP fused: act2 = swiglu(h2 @ gu_m^T)  (768 blocks, 128x64)
    gemm_swiglu<<<dim3(INTER_M / 64, 4096 / 128), 256, 0, stream>>>(
        h2_bf, w_gum, act2, 4096, INTER_M, 512);

    // 14) down_m GEMM, split-K x4 -> partials in skbuf
    gemm_bt_sk<<<dim3(512 / 128, 4096 / 128, 4), 256, 0, stream>>>(
        act2, w_downm, skbuf, 4096, 512, 1536, 384);

    // 15) out = rms(h2_f + sum partials)
    residual_rms_sk_kernel<<<4096, 128, 0, stream>>>(h2_f, skbuf, outp, 512, 4096);
}

// Round 16
// 356.063 us; speedup vs baseline: 1.2293x; 1.0356x over previous
//
#include <hip/hip_runtime.h>

// ---------------------------------------------------------------------------
// Mamba2 hybrid block. GEMMs: bf16 MFMA 16x16x32, f32 accumulate, m97-style
// global_load_lds(16B) staging, BK=64 (R15: single-buffered K-loop is ~53%
// barrier drain at 2-3 blocks/CU; 64-wide K tiles halve barrier count.
// 3-bit XOR chunk swizzle keeps frag reads 2-way/free). Small-N GEMMs use
// split-K x4 into SEPARATE partial buffers; partials summed in the
// downstream residual_rms kernel. MLP gu-GEMMs fuse SwiGLU (128x64 act tile;
// R14: acc must stay <=16 f32x4 or VGPR cliff). Scan: MFMA chunked.
// ---------------------------------------------------------------------------

#define BB 4
#define LL 1024
#define DMODEL 512
#define DINNER 1024
#define NHEADS 16
#define HEADDIM 64
#define DSTATE 64
#define CONVDIM 1152        // DINNER + 2*DSTATE
#define NPROJ 2192          // D_IN_PROJ
#define NPROJ_PAD 2304      // padded to multiple of 128
#define INTER_T 2816
#define INTER_M 1536
#define NCHUNK 32
#define CHUNK 32

typedef __bf16 bf16x8 __attribute__((ext_vector_type(8)));
typedef float  f32x4  __attribute__((ext_vector_type(4)));
typedef unsigned short u16;
typedef unsigned int   u32;

__device__ __forceinline__ u16 f2bf(float x) {
    union { float f; u32 u; } v; v.f = x;
    u32 u = v.u;
    return (u16)((u + 0x7fffu + ((u >> 16) & 1u)) >> 16);
}
__device__ __forceinline__ float silu_f(float x) {
    return x / (1.f + __expf(-x));
}
__device__ __forceinline__ float bf2f(u16 w) {
    union { u32 u; float f; } a; a.u = ((u32)w) << 16; return a.f;
}

// async global->LDS, 16B per lane; LDS dest is wave-uniform base + lane*16
__device__ __forceinline__ void gld_lds16(const u16* g, u16* l) {
    __builtin_amdgcn_global_load_lds(
        (const __attribute__((address_space(1))) unsigned int*)g,
        (__attribute__((address_space(3))) unsigned int*)l, 16, 0, 0);
}

// --------------------------- block-wide sum --------------------------------
__device__ __forceinline__ float block_sum(float v) {
    #pragma unroll
    for (int off = 32; off > 0; off >>= 1) v += __shfl_xor(v, off, 64);
    __shared__ float red[4];
    int w = threadIdx.x >> 6;
    int nwv = blockDim.x >> 6;
    if ((threadIdx.x & 63) == 0) red[w] = v;
    __syncthreads();
    float tot = red[0];
    for (int i = 1; i < nwv; i++) tot += red[i];
    return tot;
}

// --------------------- f32 -> bf16 convert (all weights + hidden) ----------
#define HID_E      2097152LL   // 4096*512
#define INPROJ_P_E 1179648LL   // 2304*512
#define INPROJ_S_E 1122304LL   // 2192*512
#define OUTPROJ_E   524288LL   // 512*1024
#define GUT_E      5767168LL   // 5632*1024
#define DOWNT_E    2883584LL   // 1024*2816
#define GUM_E      1572864LL   // 3072*512
#define DOWNM_E     786432LL   // 512*1536
#define CONV_TOT_E 14811136LL

__global__ __launch_bounds__(256) void convert_all_kernel(
    const float* __restrict__ s_hid, const float* __restrict__ s_inproj,
    const float* __restrict__ s_outproj, const float* __restrict__ s_gut,
    const float* __restrict__ s_downt, const float* __restrict__ s_gum,
    const float* __restrict__ s_downm, u16* __restrict__ dst)
{
    long long idx = (long long)blockIdx.x * 256 + threadIdx.x;
    long long e = idx * 4;
    if (e >= CONV_TOT_E) return;
    const float* src; long long off, nsrc;
    long long c0 = HID_E;
    long long c1 = c0 + INPROJ_P_E;
    long long c2 = c1 + OUTPROJ_E;
    long long c3 = c2 + GUT_E;
    long long c4 = c3 + DOWNT_E;
    long long c5 = c4 + GUM_E;
    if      (e < c0) { src = s_hid;     off = e;      nsrc = HID_E; }
    else if (e < c1) { src = s_inproj;  off = e - c0; nsrc = INPROJ_S_E; }
    else if (e < c2) { src = s_outproj; off = e - c1; nsrc = OUTPROJ_E; }
    else if (e < c3) { src = s_gut;     off = e - c2; nsrc = GUT_E; }
    else if (e < c4) { src = s_downt;   off = e - c3; nsrc = DOWNT_E; }
    else if (e < c5) { src = s_gum;     off = e - c4; nsrc = GUM_E; }
    else             { src = s_downm;   off = e - c5; nsrc = DOWNM_E; }
    ushort4 r;
    if (off < nsrc) {
        float4 v = *reinterpret_cast<const float4*>(src + off);
        r.x = f2bf(v.x); r.y = f2bf(v.y); r.z = f2bf(v.z); r.w = f2bf(v.w);
    } else {
        r.x = 0; r.y = 0; r.z = 0; r.w = 0;
    }
    *reinterpret_cast<ushort4*>(dst + e) = r;
}

// ----------------------------- bf16 MFMA GEMM (BK=64) ----------------------
// C[M,N] = A[M,K] * W[N,K]^T. 128x128 tile, 4 waves of 64x64 (4x4 MFMAs).
// LDS rows are 64 u16 (128 B); staging: 8 rows x 8 chunks of 16B per inst,
// global chunk = cL ^ rL (3-bit XOR). Frag chunk = (ks*4+kq) ^ (lrow&7).
template<bool SK>
__device__ __forceinline__ void gemm_bt_body(
    const u16* __restrict__ A, const u16* __restrict__ W,
    float* __restrict__ C, int M, int N, int K, int kLen)
{
    __shared__ u16 As[128 * 64];   // 16 KB
    __shared__ u16 Bs[128 * 64];   // 16 KB
    int tid = threadIdx.x;
    int m0 = blockIdx.y * 128, n0 = blockIdx.x * 128;
    int kBase = SK ? blockIdx.z * kLen : 0;
    float* Cw = SK ? C + (size_t)blockIdx.z * M * N : C;
    int wave = tid >> 6, lane = tid & 63;
    int wm = (wave >> 1) * 64, wn = (wave & 1) * 64;
    int lrow = lane & 15;
    int kq = lane >> 4;
    int kx = lrow & 7;

    int rL = lane >> 3, cL = lane & 7;
    int cG = cL ^ rL;
    const u16* gA[4]; const u16* gB[4];
    u16 *lA[4], *lB[4];
    #pragma unroll
    for (int i = 0; i < 4; i++) {
        int r = wave * 32 + i * 8;
        gA[i] = A + (size_t)(m0 + r + rL) * K + kBase + cG * 8;
        gB[i] = W + (size_t)(n0 + r + rL) * K + kBase + cG * 8;
        lA[i] = &As[r * 64];
        lB[i] = &Bs[r * 64];
    }

    f32x4 acc[4][4];
    #pragma unroll
    for (int i = 0; i < 4; i++)
        #pragma unroll
        for (int j = 0; j < 4; j++) {
            acc[i][j][0] = 0.f; acc[i][j][1] = 0.f;
            acc[i][j][2] = 0.f; acc[i][j][3] = 0.f;
        }

    for (int kt = 0; kt < kLen; kt += 64) {
        __syncthreads();
        #pragma unroll
        for (int i = 0; i < 4; i++) {
            gld_lds16(gA[i] + kt, lA[i]);
            gld_lds16(gB[i] + kt, lB[i]);
        }
        __syncthreads();
        #pragma unroll
        for (int ks = 0; ks < 2; ks++) {
            int ko = (((ks * 4 + kq) ^ kx) * 8);
            bf16x8 af[4], bfr[4];
            #pragma unroll
            for (int i = 0; i < 4; i++) {
                af[i]  = *reinterpret_cast<const bf16x8*>(&As[(wm + i * 16 + lrow) * 64 + ko]);
                bfr[i] = *reinterpret_cast<const bf16x8*>(&Bs[(wn + i * 16 + lrow) * 64 + ko]);
            }
            #pragma unroll
            for (int i = 0; i < 4; i++)
                #pragma unroll
                for (int j = 0; j < 4; j++)
                    acc[i][j] = __builtin_amdgcn_mfma_f32_16x16x32_bf16(af[i], bfr[j], acc[i][j], 0, 0, 0);
        }
    }

    // C/D layout: col = lane&15, row = (lane>>4)*4 + reg
    int rbase = m0 + wm + kq * 4;
    int cbase = n0 + wn + lrow;
    #pragma unroll
    for (int i = 0; i < 4; i++)
        #pragma unroll
        for (int j = 0; j < 4; j++)
            #pragma unroll
            for (int r = 0; r < 4; r++)
                Cw[(size_t)(rbase + i * 16 + r) * N + cbase + j * 16] = acc[i][j][r];
}

__global__ __launch_bounds__(256) void gemm_bt(
    const u16* __restrict__ A, const u16* __restrict__ W,
    float* __restrict__ C, int M, int N, int K)
{
    gemm_bt_body<false>(A, W, C, M, N, K, K);
}

__global__ __launch_bounds__(256) void gemm_bt_sk(
    const u16* __restrict__ A, const u16* __restrict__ W,
    float* __restrict__ C, int M, int N, int K, int kLen)
{
    gemm_bt_body<true>(A, W, C, M, N, K, kLen);
}

// --------------- fused gate/up GEMM + SwiGLU (128x64, BK=64) ---------------
// act[M,inter] = silu(A·Wg^T) * (A·Wu^T). Bs rows 0..63 = gate, 64..127 = up.
__global__ __launch_bounds__(256) void gemm_swiglu(
    const u16* __restrict__ A, const u16* __restrict__ W,
    u16* __restrict__ act, int M, int inter, int K)
{
    __shared__ u16 As[128 * 64];   // 16 KB
    __shared__ u16 Bs[128 * 64];   // 16 KB
    int tid = threadIdx.x;
    int m0 = blockIdx.y * 128, n0 = blockIdx.x * 64;
    int wave = tid >> 6, lane = tid & 63;
    int wm = (wave >> 1) * 64, wn = (wave & 1) * 32;
    int lrow = lane & 15;
    int kq = lane >> 4;
    int kx = lrow & 7;

    int rL = lane >> 3, cL = lane & 7;
    int cG = cL ^ rL;
    const u16* gA[4]; const u16* gB[4];
    u16 *lA[4], *lB[4];
    #pragma unroll
    for (int i = 0; i < 4; i++) {
        int r = wave * 32 + i * 8;
        gA[i] = A + (size_t)(m0 + r + rL) * K + cG * 8;
        lA[i] = &As[r * 64];
        int rB = r;   // combined index: 0..63 gate, 64..127 up (per wave 32)
        int grow = (rB < 64) ? (n0 + rB + rL)
                             : (inter + n0 + rB - 64 + rL);
        gB[i] = W + (size_t)grow * K + cG * 8;
        lB[i] = &Bs[rB * 64];
    }

    f32x4 accg[4][2], accu[4][2];
    #pragma unroll
    for (int i = 0; i < 4; i++)
        #pragma unroll
        for (int j = 0; j < 2; j++) {
            accg[i][j][0]=0.f; accg[i][j][1]=0.f; accg[i][j][2]=0.f; accg[i][j][3]=0.f;
            accu[i][j][0]=0.f; accu[i][j][1]=0.f; accu[i][j][2]=0.f; accu[i][j][3]=0.f;
        }

    for (int kt = 0; kt < K; kt += 64) {
        __syncthreads();
        #pragma unroll
        for (int i = 0; i < 4; i++) {
            gld_lds16(gA[i] + kt, lA[i]);
            gld_lds16(gB[i] + kt, lB[i]);
        }
        __syncthreads();
        #pragma unroll
        for (int ks = 0; ks < 2; ks++) {
            int ko = (((ks * 4 + kq) ^ kx) * 8);
            bf16x8 af[4], bg[2], bu[2];
            #pragma unroll
            for (int i = 0; i < 4; i++)
                af[i] = *reinterpret_cast<const bf16x8*>(&As[(wm + i * 16 + lrow) * 64 + ko]);
            #pragma unroll
            for (int j = 0; j < 2; j++) {
                bg[j] = *reinterpret_cast<const bf16x8*>(&Bs[(wn + j * 16 + lrow) * 64 + ko]);
                bu[j] = *reinterpret_cast<const bf16x8*>(&Bs[(64 + wn + j * 16 + lrow) * 64 + ko]);
            }
            #pragma unroll
            for (int i = 0; i < 4; i++)
                #pragma unroll
                for (int j = 0; j < 2; j++) {
                    accg[i][j] = __builtin_amdgcn_mfma_f32_16x16x32_bf16(af[i], bg[j], accg[i][j], 0, 0, 0);
                    accu[i][j] = __builtin_amdgcn_mfma_f32_16x16x32_bf16(af[i], bu[j], accu[i][j], 0, 0, 0);
                }
        }
    }

    int rbase = m0 + wm + kq * 4;
    int cbase = n0 + wn + lrow;
    #pragma unroll
    for (int i = 0; i < 4; i++)
        #pragma unroll
        for (int j = 0; j < 2; j++)
            #pragma unroll
            for (int r = 0; r < 4; r++) {
                float g = accg[i][j][r], u = accu[i][j][r];
                act[(size_t)(rbase + i * 16 + r) * inter + cbase + j * 16] =
                    f2bf(silu_f(g) * u);
            }
}

// ----------------- conv (depthwise, causal, width 4) + dt ------------------
__global__ __launch_bounds__(256) void conv_dt_kernel(
    const float* __restrict__ zx, const float* __restrict__ conv_w,
    const float* __restrict__ conv_b, const float* __restrict__ dt_bias,
    float* __restrict__ convout, float* __restrict__ dtbuf)
{
    int idx = blockIdx.x * 256 + threadIdx.x;   // over 4096*1168
    int bl = idx / 1168;
    int c  = idx - bl * 1168;
    int l  = bl & (LL - 1);
    if (c < CONVDIM) {
        const float* col = zx + (size_t)bl * NPROJ_PAD + DINNER + c;
        float acc = conv_b[c];
        #pragma unroll
        for (int i = 0; i < 4; i++) {
            int lt = l - 3 + i;
            float v = (lt >= 0) ? col[(long long)(lt - l) * NPROJ_PAD] : 0.f;
            acc = fmaf(v, conv_w[c * 4 + i], acc);
        }
        convout[(size_t)bl * CONVDIM + c] = silu_f(acc);
    } else {
        int h = c - CONVDIM;
        float v = zx[(size_t)bl * NPROJ_PAD + 2176 + h] + dt_bias[h];
        float sp = (v > 20.f) ? v : log1pf(__expf(v));
        dtbuf[(size_t)bl * NHEADS + h] = sp;
    }
}

// -------------------- MFMA chunk scan: pass 1 ------------------------------
__global__ __launch_bounds__(64) void scan_mfma1(
    const float* __restrict__ convout, const float* __restrict__ dtbuf,
    const float* __restrict__ A_log, float* __restrict__ Sc,
    float* __restrict__ Ptot, float* __restrict__ yp0)
{
    __shared__ u16 Blds[32 * 72];    // raw B bf16 [t][n]
    __shared__ u16 Clds[32 * 72];    // raw C bf16 [t][n]
    __shared__ u16 Xt[64 * 40];      // x^T bf16 [p][t]
    __shared__ u16 Bht[64 * 40];     // (w_t*dt_t*B)^T bf16 [n][t]
    __shared__ u16 Wlds[32 * 40];    // W bf16 [t][t']
    __shared__ float dtl[32], cuml[32], warr[32];

    int blk = blockIdx.x;
    int c   = blk & 31;
    int bh  = blk >> 5;
    int b = bh >> 4, h = bh & 15;
    int lane = threadIdx.x;
    int lrow = lane & 15, kq = lane >> 4;
    size_t base = ((size_t)b * LL + (size_t)c * CHUNK) * CONVDIM;
    float Ah = -__expf(A_log[h]);

    if (lane < 32)
        dtl[lane] = dtbuf[((size_t)b * LL + (size_t)c * CHUNK + lane) * NHEADS + h];
    #pragma unroll
    for (int it = 0; it < 16; ++it) {
        int idx = it * 64 + lane;
        int t = idx >> 5, q = idx & 31;
        float4 v = *reinterpret_cast<const float4*>(
            &convout[base + (size_t)t * CONVDIM + DINNER + q * 4]);
        ushort4 r4; r4.x = f2bf(v.x); r4.y = f2bf(v.y); r4.z = f2bf(v.z); r4.w = f2bf(v.w);
        if (q < 16) *reinterpret_cast<ushort4*>(&Blds[t * 72 + q * 4]) = r4;
        else        *reinterpret_cast<ushort4*>(&Clds[t * 72 + (q - 16) * 4]) = r4;
    }
    #pragma unroll
    for (int t = 0; t < 32; ++t) {
        float v = convout[base + (size_t)t * CONVDIM + h * HEADDIM + lane];
        Xt[lane * 40 + t] = f2bf(v);
    }
    __syncthreads();

    float s_inc = 0.f, s_all = 0.f;
    #pragma unroll
    for (int j = 0; j < 32; ++j) {
        float v = dtl[j];
        s_all += v;
        if (j <= lane) s_inc += v;
    }
    if (lane < 32) {
        cuml[lane] = s_inc;
        warr[lane] = __expf(Ah * (s_all - s_inc)) * dtl[lane];
    }
    float cumTot = s_all;
    __syncthreads();

    #pragma unroll
    for (int t = 0; t < 32; ++t)
        Bht[lane * 40 + t] = f2bf(warr[t] * bf2f(Blds[t * 72 + lane]));

    f32x4 accG[2][2];
    #pragma unroll
    for (int i = 0; i < 2; i++)
        #pragma unroll
        for (int j = 0; j < 2; j++) {
            accG[i][j][0]=0.f; accG[i][j][1]=0.f; accG[i][j][2]=0.f; accG[i][j][3]=0.f;
        }
    #pragma unroll
    for (int ks = 0; ks < 2; ++ks) {
        bf16x8 af[2], bfr[2];
        #pragma unroll
        for (int i = 0; i < 2; i++) {
            af[i]  = *reinterpret_cast<const bf16x8*>(&Clds[(16*i + lrow) * 72 + ks*32 + kq*8]);
            bfr[i] = *reinterpret_cast<const bf16x8*>(&Blds[(16*i + lrow) * 72 + ks*32 + kq*8]);
        }
        #pragma unroll
        for (int i = 0; i < 2; i++)
            #pragma unroll
            for (int j = 0; j < 2; j++)
                accG[i][j] = __builtin_amdgcn_mfma_f32_16x16x32_bf16(af[i], bfr[j], accG[i][j], 0, 0, 0);
    }

    float ctp0 = cuml[lrow],      dtp0 = dtl[lrow];
    float ctp1 = cuml[16 + lrow], dtp1 = dtl[16 + lrow];
    #pragma unroll
    for (int i = 0; i < 2; i++)
        #pragma unroll
        for (int r = 0; r < 4; r++) {
            int t = 16*i + kq*4 + r;
            float ct = cuml[t];
            #pragma unroll
            for (int j = 0; j < 2; j++) {
                int tp = 16*j + lrow;
                float ctp = j ? ctp1 : ctp0;
                float dtp = j ? dtp1 : dtp0;
                float g = accG[i][j][r];
                float wv = (tp <= t) ? __expf(Ah * (ct - ctp)) * dtp * g : 0.f;
                Wlds[t * 40 + tp] = f2bf(wv);
            }
        }
    __syncthreads();

    bf16x8 xf[4];
    #pragma unroll
    for (int j = 0; j < 4; j++)
        xf[j] = *reinterpret_cast<const bf16x8*>(&Xt[(16*j + lrow) * 40 + kq*8]);
    f32x4 accY[2][4];
    #pragma unroll
    for (int i = 0; i < 2; i++) {
        bf16x8 wf = *reinterpret_cast<const bf16x8*>(&Wlds[(16*i + lrow) * 40 + kq*8]);
        #pragma unroll
        for (int j = 0; j < 4; j++) {
            accY[i][j][0]=0.f; accY[i][j][1]=0.f; accY[i][j][2]=0.f; accY[i][j][3]=0.f;
            accY[i][j] = __builtin_amdgcn_mfma_f32_16x16x32_bf16(wf, xf[j], accY[i][j], 0, 0, 0);
        }
    }

    f32x4 accS[4][4];
    #pragma unroll
    for (int j = 0; j < 4; j++) {
        bf16x8 bb = *reinterpret_cast<const bf16x8*>(&Bht[(16*j + lrow) * 40 + kq*8]);
        #pragma unroll
        for (int i = 0; i < 4; i++) {
            accS[i][j][0]=0.f; accS[i][j][1]=0.f; accS[i][j][2]=0.f; accS[i][j][3]=0.f;
            accS[i][j] = __builtin_amdgcn_mfma_f32_16x16x32_bf16(xf[i], bb, accS[i][j], 0, 0, 0);
        }
    }

    float* yb = yp0 + ((size_t)b * LL + (size_t)c * CHUNK) * DINNER + h * HEADDIM;
    #pragma unroll
    for (int i = 0; i < 2; i++)
        #pragma unroll
        for (int r = 0; r < 4; r++) {
            int t = 16*i + kq*4 + r;
            #pragma unroll
            for (int j = 0; j < 4; j++)
                yb[(size_t)t * DINNER + 16*j + lrow] = accY[i][j][r];
        }
    #pragma unroll
    for (int i = 0; i < 4; i++)
        #pragma unroll
        for (int r = 0; r < 4; r++) {
            int p = 16*i + kq*4 + r;
            #pragma unroll
            for (int j = 0; j < 4; j++)
                Sc[((size_t)(bh * 4 + j) * NCHUNK + c) * 1024 + p * 16 + lrow] = accS[i][j][r];
        }
    if (lane == 0) Ptot[bh * NCHUNK + c] = __expf(Ah * cumTot);
}

// ----------------------- chunked SSM scan: combine -------------------------
__global__ __launch_bounds__(64) void scan_combine(
    const float* __restrict__ Sc, const float* __restrict__ Ptot,
    float* __restrict__ Sinit)
{
    int blk = blockIdx.x;
    int bh = blk >> 2;
    int p = threadIdx.x;
    float carry[16];
    #pragma unroll
    for (int j = 0; j < 16; j++) carry[j] = 0.f;
    for (int c = 0; c < NCHUNK; ++c) {
        size_t row = ((size_t)blk * NCHUNK + c) * 1024 + p * 16;
        float* o = Sinit + row;
        #pragma unroll
        for (int j = 0; j < 16; j++) o[j] = carry[j];
        float P = Ptot[bh * NCHUNK + c];
        const float* si = Sc + row;
        #pragma unroll
        for (int j = 0; j < 16; j++) carry[j] = fmaf(carry[j], P, si[j]);
    }
}

// -------------------- MFMA chunk scan: pass 2 ------------------------------
__global__ __launch_bounds__(64) void scan_mfma2(
    const float* __restrict__ convout, const float* __restrict__ dtbuf,
    const float* __restrict__ A_log, const float* __restrict__ Sinit,
    float* __restrict__ yp1)
{
    __shared__ u16 Clds2[32 * 72];   // dAcum-scaled C bf16 [t][n]
    __shared__ float dtl[32], dacl[32];
    int blk = blockIdx.x;
    int c   = blk & 31;
    int bh  = blk >> 5;
    int b = bh >> 4, h = bh & 15;
    int lane = threadIdx.x;
    int lrow = lane & 15, kq = lane >> 4;
    size_t base = ((size_t)b * LL + (size_t)c * CHUNK) * CONVDIM;
    float Ah = -__expf(A_log[h]);

    if (lane < 32)
        dtl[lane] = dtbuf[((size_t)b * LL + (size_t)c * CHUNK + lane) * NHEADS + h];
    __syncthreads();
    float s_inc = 0.f;
    #pragma unroll
    for (int j = 0; j < 32; ++j) {
        float v = dtl[j];
        if (j <= lane) s_inc += v;
    }
    if (lane < 32) dacl[lane] = __expf(Ah * s_inc);
    __syncthreads();
    #pragma unroll
    for (int it = 0; it < 8; ++it) {
        int idx = it * 64 + lane;
        int t = idx >> 4, q = idx & 15;
        float sc = dacl[t];
        float4 v = *reinterpret_cast<const float4*>(
            &convout[base + (size_t)t * CONVDIM + DINNER + DSTATE + q * 4]);
        ushort4 r4;
        r4.x = f2bf(v.x * sc); r4.y = f2bf(v.y * sc);
        r4.z = f2bf(v.z * sc); r4.w = f2bf(v.w * sc);
        *reinterpret_cast<ushort4*>(&Clds2[t * 72 + q * 4]) = r4;
    }
    __syncthreads();

    f32x4 accI[2][4];
    #pragma unroll
    for (int i = 0; i < 2; i++)
        #pragma unroll
        for (int j = 0; j < 4; j++) {
            accI[i][j][0]=0.f; accI[i][j][1]=0.f; accI[i][j][2]=0.f; accI[i][j][3]=0.f;
        }
    #pragma unroll
    for (int ks = 0; ks < 2; ++ks) {
        bf16x8 ca[2];
        #pragma unroll
        for (int i = 0; i < 2; i++)
            ca[i] = *reinterpret_cast<const bf16x8*>(&Clds2[(16*i + lrow) * 72 + ks*32 + kq*8]);
        int nq = ks * 2 + (kq >> 1);
        int off = (kq & 1) * 8;
        #pragma unroll
        for (int j = 0; j < 4; j++) {
            int p = 16*j + lrow;
            const float* sp = Sinit + ((size_t)(bh * 4 + nq) * NCHUNK + c) * 1024 + p * 16 + off;
            float4 a = *reinterpret_cast<const float4*>(sp);
            float4 b4 = *reinterpret_cast<const float4*>(sp + 4);
            union { u16 us[8]; bf16x8 v; } fr;
            fr.us[0] = f2bf(a.x);  fr.us[1] = f2bf(a.y);
            fr.us[2] = f2bf(a.z);  fr.us[3] = f2bf(a.w);
            fr.us[4] = f2bf(b4.x); fr.us[5] = f2bf(b4.y);
            fr.us[6] = f2bf(b4.z); fr.us[7] = f2bf(b4.w);
            #pragma unroll
            for (int i = 0; i < 2; i++)
                accI[i][j] = __builtin_amdgcn_mfma_f32_16x16x32_bf16(ca[i], fr.v, accI[i][j], 0, 0, 0);
        }
    }

    float* yb = yp1 + ((size_t)b * LL + (size_t)c * CHUNK) * DINNER + h * HEADDIM;
    #pragma unroll
    for (int i = 0; i < 2; i++)
        #pragma unroll
        for (int r = 0; r < 4; r++) {
            int t = 16*i + kq*4 + r;
            #pragma unroll
            for (int j = 0; j < 4; j++)
                yb[(size_t)t * DINNER + 16*j + lrow] = accI[i][j][r];
        }
}

// ------------- gated RMSNorm (yp0+yp1+xD)*silu(z), bf16 out ----------------
__global__ __launch_bounds__(256) void gated_rms_kernel(
    const float* __restrict__ yp0, const float* __restrict__ yp1,
    const float* __restrict__ convout, const float* __restrict__ zx,
    const float* __restrict__ Dv, const float* __restrict__ norm_w,
    u16* __restrict__ gout)
{
    int bl = blockIdx.x;
    int c = threadIdx.x * 4;
    float4 y0 = *reinterpret_cast<const float4*>(yp0 + (size_t)bl * DINNER + c);
    float4 y1 = *reinterpret_cast<const float4*>(yp1 + (size_t)bl * DINNER + c);
    float4 xv = *reinterpret_cast<const float4*>(convout + (size_t)bl * CONVDIM + c);
    float4 zv = *reinterpret_cast<const float4*>(zx + (size_t)bl * NPROJ_PAD + c);
    float Dh = Dv[c >> 6];
    float g0 = (y0.x + y1.x + xv.x * Dh) * silu_f(zv.x);
    float g1 = (y0.y + y1.y + xv.y * Dh) * silu_f(zv.y);
    float g2 = (y0.z + y1.z + xv.z * Dh) * silu_f(zv.z);
    float g3 = (y0.w + y1.w + xv.w * Dh) * silu_f(zv.w);
    float tot = block_sum(g0 * g0 + g1 * g1 + g2 * g2 + g3 * g3);
    float sc = rsqrtf(tot * (1.f / DINNER) + 1e-5f);
    float4 nw = *reinterpret_cast<const float4*>(norm_w + c);
    ushort4 o;
    o.x = f2bf(g0 * sc * nw.x); o.y = f2bf(g1 * sc * nw.y);
    o.z = f2bf(g2 * sc * nw.z); o.w = f2bf(g3 * sc * nw.w);
    *reinterpret_cast<ushort4*>(gout + (size_t)bl * DINNER + c) = o;
}

// ---- residual + 4 split-K partials + RMSNorm (no weight), f32 out ---------
__global__ void residual_rms_sk_kernel(
    const float* __restrict__ a, const float* __restrict__ pbuf,
    float* __restrict__ outf, int ncols, int rows)
{
    int row = blockIdx.x;
    int c = threadIdx.x * 4;
    size_t slice = (size_t)rows * ncols;
    size_t off = (size_t)row * ncols + c;
    float4 va = *reinterpret_cast<const float4*>(a + off);
    float4 p0 = *reinterpret_cast<const float4*>(pbuf + off);
    float4 p1 = *reinterpret_cast<const float4*>(pbuf + slice + off);
    float4 p2 = *reinterpret_cast<const float4*>(pbuf + 2 * slice + off);
    float4 p3 = *reinterpret_cast<const float4*>(pbuf + 3 * slice + off);
    float v0 = va.x + ((p0.x + p1.x) + (p2.x + p3.x));
    float v1 = va.y + ((p0.y + p1.y) + (p2.y + p3.y));
    float v2 = va.z + ((p0.z + p1.z) + (p2.z + p3.z));
    float v3 = va.w + ((p0.w + p1.w) + (p2.w + p3.w));
    float tot = block_sum(v0 * v0 + v1 * v1 + v2 * v2 + v3 * v3);
    float sc = rsqrtf(tot / (float)ncols + 1e-5f);
    float4 o; o.x = v0 * sc; o.y = v1 * sc; o.z = v2 * sc; o.w = v3 * sc;
    *reinterpret_cast<float4*>(outf + off) = o;
}

// ------------- transpose per batch: in (R,C) -> out (C,R), dual write ------
__global__ __launch_bounds__(256) void transpose_dual_kernel(
    const float* __restrict__ in, u16* __restrict__ outb,
    float* __restrict__ outf, int R, int C)
{
    __shared__ float tile[32][33];
    int b = blockIdx.z;
    int c0 = blockIdx.x * 32, r0 = blockIdx.y * 32;
    const float* ip = in + (size_t)b * R * C;
    for (int i = threadIdx.y; i < 32; i += 8)
        tile[i][threadIdx.x] = ip[(size_t)(r0 + i) * C + c0 + threadIdx.x];
    __syncthreads();
    size_t ob = (size_t)b * R * C;
    for (int i = threadIdx.y; i < 32; i += 8) {
        float v = tile[threadIdx.x][i];
        size_t oi = ob + (size_t)(c0 + i) * R + r0 + threadIdx.x;
        outf[oi] = v;
        outb[oi] = f2bf(v);
    }
}

// ---------------------------------------------------------------------------
extern "C" void kernel_launch(void* const* d_in, const int* in_sizes, int n_in,
                              void* d_out, int out_size, void* d_ws, size_t ws_size,
                              hipStream_t stream)
{
    const float* hid      = (const float*)d_in[0];
    const float* in_proj  = (const float*)d_in[1];
    const float* conv_w   = (const float*)d_in[2];
    const float* conv_b   = (const float*)d_in[3];
    const float* dt_bias  = (const float*)d_in[4];
    const float* A_log    = (const float*)d_in[5];
    const float* Dv       = (const float*)d_in[6];
    const float* norm_w   = (const float*)d_in[7];
    const float* out_proj = (const float*)d_in[8];
    const float* gu_t     = (const float*)d_in[9];
    const float* down_t   = (const float*)d_in[10];
    const float* gu_m     = (const float*)d_in[11];
    const float* down_m   = (const float*)d_in[12];
    float* outp = (float*)d_out;

    char* ws = (char*)d_ws;
    u16* bf        = (u16*)ws;
    u16* hid_bf    = bf;
    u16* w_inproj  = bf + HID_E;
    u16* w_outproj = w_inproj + INPROJ_P_E;
    u16* w_gut     = w_outproj + OUTPROJ_E;
    u16* w_downt   = w_gut + GUT_E;
    u16* w_gum     = w_downt + DOWNT_E;
    u16* w_downm   = w_gum + GUM_E;
    size_t o = (size_t)(CONV_TOT_E * 2);
    auto alloc = [&](size_t bytes) { size_t r = o; o = (o + bytes + 255) & ~(size_t)255; return r; };
    size_t dt_off  = alloc(4096 * 16 * 4);
    size_t g_off   = alloc((size_t)4096 * 1024 * 2);
    size_t h1_off  = alloc((size_t)4096 * 512 * 4);
    size_t Pt_off  = alloc(2048 * 4);
    // ---- MLP region (live step 8+); Sc/Sinit OVERLAY it (live steps 4-5).
    size_t xtb_off = alloc((size_t)2048 * 1024 * 2);
    size_t xtf_off = alloc((size_t)2048 * 1024 * 4);
    size_t act1_off= alloc((size_t)2048 * 2816 * 2);
    size_t x2_off  = alloc((size_t)2048 * 1024 * 4);
    size_t h2b_off = alloc((size_t)4096 * 512 * 2);
    size_t h2f_off = alloc((size_t)4096 * 512 * 4);
    size_t act2_off= alloc((size_t)4096 * 1536 * 2);
    size_t pad_off = alloc((size_t)10 * 1024 * 1024);
    size_t Sc_off  = xtb_off;                          // 33.55 MB
    size_t Si_off  = xtb_off + (size_t)8192 * 1024 * 4;// 33.55 MB
    (void)pad_off;
    size_t R_off   = o;
    size_t zx_off  = R_off;
    size_t cv_off  = zx_off + (size_t)4096 * NPROJ_PAD * 4;
    size_t y_off   = cv_off + (size_t)4096 * CONVDIM * 4;
    size_t sk_off  = R_off;

    float* zx      = (float*)(ws + zx_off);
    float* convout = (float*)(ws + cv_off);
    float* ybuf    = (float*)(ws + y_off);           // yp0
    float* dtbuf   = (float*)(ws + dt_off);
    u16*   g_bf    = (u16*)(ws + g_off);
    float* h1      = (float*)(ws + h1_off);
    u16*   xt_bf   = (u16*)(ws + xtb_off);
    float* xt_f    = (float*)(ws + xtf_off);
    u16*   act1    = (u16*)(ws + act1_off);
    float* x2      = (float*)(ws + x2_off);
    u16*   h2_bf   = (u16*)(ws + h2b_off);
    float* h2_f    = (float*)(ws + h2f_off);
    u16*   act2    = (u16*)(ws + act2_off);
    float* skbuf   = (float*)(ws + sk_off);
    float* Sc      = (float*)(ws + Sc_off);          // yp1 after scan_combine
    float* Sinit   = (float*)(ws + Si_off);
    float* Ptot    = (float*)(ws + Pt_off);

    // 1) convert weights + hidden to bf16
    convert_all_kernel<<<14464, 256, 0, stream>>>(
        hid, in_proj, out_proj, gu_t, down_t, gu_m, down_m, bf);

    // 2) zxbcdt = hidden @ in_proj^T
    gemm_bt<<<dim3(NPROJ_PAD / 128, 4096 / 128), 256, 0, stream>>>(
        hid_bf, w_inproj, zx, 4096, NPROJ_PAD, 512);

    // 3) conv + dt
    conv_dt_kernel<<<18688, 256, 0, stream>>>(zx, conv_w, conv_b, dt_bias, convout, dtbuf);

    // 4) MFMA chunk scan
    scan_mfma1<<<2048, 64, 0, stream>>>(convout, dtbuf, A_log, Sc, Ptot, ybuf);
    scan_combine<<<256, 64, 0, stream>>>(Sc, Ptot, Sinit);
    scan_mfma2<<<2048, 64, 0, stream>>>(convout, dtbuf, A_log, Sinit, Sc);

    // 5) gated RMSNorm -> bf16
    gated_rms_kernel<<<4096, 256, 0, stream>>>(ybuf, Sc, convout, zx, Dv, norm_w, g_bf);

    // 6) out_proj GEMM, split-K x4 -> partials in skbuf
    gemm_bt_sk<<<dim3(512 / 128, 4096 / 128, 4), 256, 0, stream>>>(
        g_bf, w_outproj, skbuf, 4096, 512, 1024, 256);

    // 7) h1 = rms(hidden + sum partials)
    residual_rms_sk_kernel<<<4096, 128, 0, stream>>>(hid, skbuf, h1, 512, 4096);

    // 8) transpose (B,1024,512) -> (B,512,1024)
    transpose_dual_kernel<<<dim3(16, 32, 4), dim3(32, 8), 0, stream>>>(h1, xt_bf, xt_f, 1024, 512);

    // 9) token MLP fused: act1 = swiglu(xt @ gu_t^T)  (704 blocks, 128x64)
    gemm_swiglu<<<dim3(INTER_T / 64, 2048 / 128), 256, 0, stream>>>(
        xt_bf, w_gut, act1, 2048, INTER_T, 1024);

    // 10) down_t GEMM, split-K x4 -> partials in skbuf
    gemm_bt_sk<<<dim3(1024 / 128, 2048 / 128, 4), 256, 0, stream>>>(
        act1, w_downt, skbuf, 2048, 1024, 2816, 704);

    // 11) x2 = rms(xt_f + sum partials)
    residual_rms_sk_kernel<<<2048, 256, 0, stream>>>(xt_f, skbuf, x2, 1024, 2048);

    // 12) transpose back (B,512,1024) -> (B,1024,512)
    transpose_dual_kernel<<<dim3(32, 16, 4), dim3(32, 8), 0, stream>>>(x2, h2_bf, h2_f, 512, 1024);

    // 13) channel MLP fused: act2 = swiglu(h2 @ gu_m^T)  (768 blocks, 128x64)
    gemm_swiglu<<<dim3(INTER_M / 64, 4096 / 128), 256, 0, stream>>>(
        h2_bf, w_gum, act2, 4096, INTER_M, 512);

    // 14) down_m GEMM, split-K x4 -> partials in skbuf
    gemm_bt_sk<<<dim3(512 / 128, 4096 / 128, 4), 256, 0, stream>>>(
        act2, w_downm, skbuf, 4096, 512, 1536, 384);

    // 15) out = rms(h2_f + sum partials)
    residual_rms_sk_kernel<<<4096, 128, 0, stream>>>(h2_f, skbuf, outp, 512, 4096);
}